// Round 1
// baseline (1341.123 us; speedup 1.0000x reference)
//
#include <hip/hip_runtime.h>
#include <stdint.h>

#define N_NODES 65536
#define N_EDGES 1048576
#define BATCH   128
#define PD      512
#define CLIPD   768

typedef __attribute__((ext_vector_type(4))) float f32x4;
typedef __attribute__((ext_vector_type(4))) int   i32x4;

__device__ __forceinline__ unsigned short f2b(float f) {
    uint32_t u = __float_as_uint(f);
    return (unsigned short)((u + 0x7fffu + ((u >> 16) & 1u)) >> 16);
}
__device__ __forceinline__ float blo(uint32_t v) { return __uint_as_float(v << 16); }
__device__ __forceinline__ float bhi(uint32_t v) { return __uint_as_float(v & 0xffff0000u); }

// ---------------- Wg transpose + cast to bf16:  WgT[n][k] = bf16(Wg[k][n]) ----------------
__global__ void k_wgt(const float* __restrict__ Wg, unsigned short* __restrict__ WgT) {
    __shared__ float tile[32][33];
    int kb = blockIdx.x * 32, nb = blockIdx.y * 32;
    int tx = threadIdx.x, ty = threadIdx.y;
    tile[ty][tx] = Wg[(size_t)(kb + ty) * PD + nb + tx];
    __syncthreads();
    WgT[(size_t)(nb + ty) * PD + kb + tx] = f2b(tile[tx][ty]);
}

// ---------------- init: deg=1 (self loop), fill=0, sums=0, cnts=0 ----------------
__global__ void k_init(int* __restrict__ deg, int* __restrict__ fill,
                       float* __restrict__ sums, int* __restrict__ cnts) {
    int i = blockIdx.x * 256 + threadIdx.x;   // 65536 threads
    deg[i] = 1;
    fill[i] = 0;
    sums[i] = 0.f;                            // 128*512 == 65536
    if (i < BATCH) cnts[i] = 0;
}

// ---------------- degree count over dst ----------------
__global__ void k_deg(const int* __restrict__ ei, int* __restrict__ deg) {
    int e = blockIdx.x * 256 + threadIdx.x;   // E threads
    atomicAdd(&deg[ei[N_EDGES + e]], 1);
}

// ---------------- nodes per batch ----------------
__global__ void k_cnt(const int* __restrict__ bv, int* __restrict__ cnts) {
    int i = blockIdx.x * 256 + threadIdx.x;
    atomicAdd(&cnts[bv[i]], 1);
}

// ---------------- single-block exclusive scan of (deg-1) + dis = rsqrt(deg) ----------------
__global__ void k_scan(const int* __restrict__ deg, int* __restrict__ row_ptr,
                       float* __restrict__ dis) {
    __shared__ int part[1024];
    int t = threadIdx.x;
    const int per = N_NODES / 1024;           // 64
    int base = t * per;
    int s = 0;
    for (int i = 0; i < per; ++i) s += deg[base + i] - 1;
    part[t] = s;
    __syncthreads();
    for (int off = 1; off < 1024; off <<= 1) {
        int v = (t >= off) ? part[t - off] : 0;
        __syncthreads();
        part[t] += v;
        __syncthreads();
    }
    int excl = (t == 0) ? 0 : part[t - 1];
    for (int i = 0; i < per; ++i) {
        int d = deg[base + i];
        row_ptr[base + i] = excl;
        excl += d - 1;
        dis[base + i] = rsqrtf((float)d);
    }
    if (t == 1023) row_ptr[N_NODES] = excl;   // == E
}

// ---------------- scatter edges into CSR buckets ----------------
__global__ void k_scatter(const int* __restrict__ ei, const int* __restrict__ row_ptr,
                          int* __restrict__ fill, int* __restrict__ srcs) {
    int e = blockIdx.x * 256 + threadIdx.x;
    int d = ei[N_EDGES + e];
    int pos = row_ptr[d] + atomicAdd(&fill[d], 1);
    srcs[pos] = ei[e];
}

// ---------------- big GEMM: hn[i] = bf16( dis[i] * (x[i] @ Wg) ) ----------------
// 128x128 tile, BK=32, 4 waves; MFMA 16x16x32 bf16 via inline asm.
__device__ __forceinline__ void mfma16(f32x4& acc, i32x4 a, i32x4 b) {
    asm("v_mfma_f32_16x16x32_bf16 %0, %1, %2, %0" : "+v"(acc) : "v"(a), "v"(b));
}

__global__ __launch_bounds__(256) void k_gemm(const float* __restrict__ X,
                                              const unsigned short* __restrict__ WgT,
                                              const float* __restrict__ dis,
                                              unsigned short* __restrict__ hn) {
    __shared__ __align__(16) unsigned short As[128 * 32];
    __shared__ __align__(16) unsigned short Bs[128 * 32];
    const int m0 = blockIdx.x * 128;
    const int n0 = blockIdx.y * 128;
    const int t = threadIdx.x;
    const int lane = t & 63, w = t >> 6;
    const int wr = w >> 1, wc = w & 1;
    const int g = lane >> 4, lr = lane & 15;

    f32x4 acc[4][4] = {};

    for (int k0 = 0; k0 < PD; k0 += 32) {
        __syncthreads();
        // stage A: 128x32 f32 -> bf16, 4 floats per thread per iter, 4 iters
#pragma unroll
        for (int it = 0; it < 4; ++it) {
            int idx = it * 256 + t;
            int r = idx >> 3, kc = (idx & 7) * 4;
            float4 v = *(const float4*)&X[(size_t)(m0 + r) * PD + k0 + kc];
            uint2 o;
            o.x = (uint32_t)f2b(v.x) | ((uint32_t)f2b(v.y) << 16);
            o.y = (uint32_t)f2b(v.z) | ((uint32_t)f2b(v.w) << 16);
            *(uint2*)&As[r * 32 + kc] = o;
        }
        // stage B (already bf16): 16B per thread per iter, 2 iters
#pragma unroll
        for (int it = 0; it < 2; ++it) {
            int idx = it * 256 + t;
            int r = idx >> 2, kc = (idx & 3) * 8;
            *(uint4*)&Bs[r * 32 + kc] = *(const uint4*)&WgT[(size_t)(n0 + r) * PD + k0 + kc];
        }
        __syncthreads();

        i32x4 a[4], b[4];
#pragma unroll
        for (int i = 0; i < 4; ++i) a[i] = *(const i32x4*)&As[(wr * 64 + i * 16 + lr) * 32 + g * 8];
#pragma unroll
        for (int j = 0; j < 4; ++j) b[j] = *(const i32x4*)&Bs[(wc * 64 + j * 16 + lr) * 32 + g * 8];
#pragma unroll
        for (int i = 0; i < 4; ++i)
#pragma unroll
            for (int j = 0; j < 4; ++j) mfma16(acc[i][j], a[i], b[j]);
    }
    // MFMA->VALU read hazard padding (inline asm: compiler can't insert waits)
    asm volatile("s_nop 7\n s_nop 7\n s_nop 7\n s_nop 7");

#pragma unroll
    for (int i = 0; i < 4; ++i) {
#pragma unroll
        for (int r = 0; r < 4; ++r) {
            int row = m0 + wr * 64 + i * 16 + g * 4 + r;
            float dd = dis[row];
#pragma unroll
            for (int j = 0; j < 4; ++j) {
                int col = n0 + wc * 64 + j * 16 + lr;
                hn[(size_t)row * PD + col] = f2b(acc[i][j][r] * dd);
            }
        }
    }
}

// ---------------- aggregation + bias + relu + fused mean-pool accumulation ----------------
#define NPB 8
__global__ __launch_bounds__(256) void k_agg(const unsigned short* __restrict__ hn,
                                             const float* __restrict__ dis,
                                             const float* __restrict__ bg,
                                             const int* __restrict__ row_ptr,
                                             const int* __restrict__ srcs,
                                             const int* __restrict__ bv,
                                             float* __restrict__ sums) {
    const int t = threadIdx.x;
    const int c0 = t * 2;
    const int node0 = blockIdx.x * NPB;
    const float bg0 = bg[c0], bg1 = bg[c0 + 1];
    float s0 = 0.f, s1 = 0.f;
    int curb = bv[node0];
    for (int ni = 0; ni < NPB; ++ni) {
        int node = node0 + ni;
        int b = bv[node];
        if (b != curb) {
            atomicAdd(&sums[(size_t)curb * PD + c0], s0);
            atomicAdd(&sums[(size_t)curb * PD + c0 + 1], s1);
            s0 = s1 = 0.f;
            curb = b;
        }
        float a0 = 0.f, a1 = 0.f;
        int beg = row_ptr[node], end = row_ptr[node + 1];
        for (int e = beg; e < end; ++e) {
            int sn = srcs[e];
            uint32_t v = *(const uint32_t*)&hn[(size_t)sn * PD + c0];
            a0 += blo(v);
            a1 += bhi(v);
        }
        uint32_t v = *(const uint32_t*)&hn[(size_t)node * PD + c0];  // self loop
        a0 += blo(v);
        a1 += bhi(v);
        float dd = dis[node];
        a0 = fmaxf(fmaf(a0, dd, bg0), 0.f);
        a1 = fmaxf(fmaf(a1, dd, bg1), 0.f);
        s0 += a0;
        s1 += a1;
    }
    atomicAdd(&sums[(size_t)curb * PD + c0], s0);
    atomicAdd(&sums[(size_t)curb * PD + c0 + 1], s1);
}

// ---------------- small dense: C[row][col] = act(A[row][:K] @ W[:,col] + bias[col]) ----------------
__global__ void k_lin(const float* __restrict__ A, const float* __restrict__ W,
                      const float* __restrict__ bias, float* __restrict__ C,
                      int K, int Ncol, int ldc, int relu) {
    int row = blockIdx.x;
    int col = blockIdx.y * 64 + threadIdx.x;
    const float* a = A + (size_t)row * K;
    float acc = bias[col];
    for (int k = 0; k < K; ++k) acc = fmaf(a[k], W[(size_t)k * Ncol + col], acc);
    if (relu) acc = fmaxf(acc, 0.f);
    C[(size_t)row * ldc + col] = acc;
}

// ---------------- dot: y[row] = A[row][:K] @ w + b ----------------
__global__ void k_dot(const float* __restrict__ A, const float* __restrict__ w,
                      const float* __restrict__ b, float* __restrict__ y, int K) {
    int row = blockIdx.x;
    int t = threadIdx.x;   // 64
    float s = 0.f;
    for (int k = t; k < K; k += 64) s = fmaf(A[(size_t)row * K + k], w[k], s);
    for (int off = 32; off; off >>= 1) s += __shfl_down(s, off);
    if (t == 0) y[row] = s + b[0];
}

// ---------------- graph features: gf = sums / max(cnts,1) ----------------
__global__ void k_gf(const float* __restrict__ sums, const int* __restrict__ cnts,
                     float* __restrict__ gf) {
    int i = blockIdx.x * 256 + threadIdx.x;   // 65536
    float c = fmaxf((float)cnts[i >> 9], 1.f);
    gf[i] = sums[i] / c;
}

// ---------------- logits + BCE loss ----------------
__global__ void k_final(const float* __restrict__ yi, const float* __restrict__ ys,
                        const float* __restrict__ ans, float* __restrict__ out) {
    __shared__ float red[128];
    int t = threadIdx.x;   // 128
    float l = fmaxf(yi[t], ys[t]);
    out[t] = l;
    float li = fmaxf(l, 0.f) + log1pf(expf(-fabsf(l))) - l * ans[t];
    red[t] = li;
    __syncthreads();
    for (int off = 64; off; off >>= 1) {
        if (t < off) red[t] += red[t + off];
        __syncthreads();
    }
    if (t == 0) out[BATCH] = red[0] / (float)BATCH;
}

extern "C" void kernel_launch(void* const* d_in, const int* in_sizes, int n_in,
                              void* d_out, int out_size, void* d_ws, size_t ws_size,
                              hipStream_t stream) {
    const float* image_features = (const float*)d_in[0];
    const float* text_features  = (const float*)d_in[1];
    const float* answer         = (const float*)d_in[2];
    const float* x_nodes        = (const float*)d_in[3];
    const int*   edge_index     = (const int*)d_in[4];
    const int*   batch_vec      = (const int*)d_in[5];
    const float* W_img = (const float*)d_in[6];
    const float* b_img = (const float*)d_in[7];
    const float* W_txt = (const float*)d_in[8];
    const float* b_txt = (const float*)d_in[9];
    const float* W1  = (const float*)d_in[10];
    const float* b1  = (const float*)d_in[11];
    const float* W2  = (const float*)d_in[12];
    const float* b2  = (const float*)d_in[13];
    const float* Wg  = (const float*)d_in[14];
    const float* bg  = (const float*)d_in[15];
    const float* Ws1 = (const float*)d_in[16];
    const float* bs1 = (const float*)d_in[17];
    const float* Ws2 = (const float*)d_in[18];
    const float* bs2 = (const float*)d_in[19];
    float* out = (float*)d_out;

    char* base = (char*)d_ws;
    size_t cur = 0;
    auto alloc = [&](size_t bytes) -> void* {
        void* r = base + cur;
        cur = (cur + bytes + 255) & ~(size_t)255;
        return r;
    };
    unsigned short* WgT = (unsigned short*)alloc((size_t)PD * PD * 2);
    unsigned short* hn  = (unsigned short*)alloc((size_t)N_NODES * PD * 2);
    int*   deg     = (int*)alloc((size_t)N_NODES * 4);
    float* dis     = (float*)alloc((size_t)N_NODES * 4);
    int*   row_ptr = (int*)alloc((size_t)(N_NODES + 1) * 4);
    int*   fill    = (int*)alloc((size_t)N_NODES * 4);
    int*   srcs    = (int*)alloc((size_t)N_EDGES * 4);
    float* sums    = (float*)alloc((size_t)BATCH * PD * 4);
    int*   cnts    = (int*)alloc((size_t)BATCH * 4);
    float* combined = (float*)alloc((size_t)BATCH * 1024 * 4);
    float* h1      = (float*)alloc((size_t)BATCH * PD * 4);
    float* gf      = (float*)alloc((size_t)BATCH * PD * 4);
    float* hs      = (float*)alloc((size_t)BATCH * PD * 4);
    float* yi      = (float*)alloc((size_t)BATCH * 4);
    float* ys      = (float*)alloc((size_t)BATCH * 4);

    // symbolic-branch preprocessing
    hipLaunchKernelGGL(k_wgt, dim3(16, 16), dim3(32, 32), 0, stream, Wg, WgT);
    hipLaunchKernelGGL(k_init, dim3(256), dim3(256), 0, stream, deg, fill, sums, cnts);
    hipLaunchKernelGGL(k_deg, dim3(4096), dim3(256), 0, stream, edge_index, deg);
    hipLaunchKernelGGL(k_cnt, dim3(256), dim3(256), 0, stream, batch_vec, cnts);
    hipLaunchKernelGGL(k_scan, dim3(1), dim3(1024), 0, stream, deg, row_ptr, dis);
    hipLaunchKernelGGL(k_scatter, dim3(4096), dim3(256), 0, stream, edge_index, row_ptr, fill, srcs);
    hipLaunchKernelGGL(k_gemm, dim3(N_NODES / 128, PD / 128), dim3(256), 0, stream,
                       x_nodes, WgT, dis, hn);
    hipLaunchKernelGGL(k_agg, dim3(N_NODES / NPB), dim3(256), 0, stream,
                       hn, dis, bg, row_ptr, srcs, batch_vec, sums);

    // implicit branch
    hipLaunchKernelGGL(k_lin, dim3(BATCH, 8), dim3(64), 0, stream,
                       image_features, W_img, b_img, combined, CLIPD, PD, 1024, 0);
    hipLaunchKernelGGL(k_lin, dim3(BATCH, 8), dim3(64), 0, stream,
                       text_features, W_txt, b_txt, combined + PD, CLIPD, PD, 1024, 0);
    hipLaunchKernelGGL(k_lin, dim3(BATCH, 8), dim3(64), 0, stream,
                       combined, W1, b1, h1, 1024, PD, PD, 1);
    hipLaunchKernelGGL(k_dot, dim3(BATCH), dim3(64), 0, stream, h1, W2, b2, yi, PD);

    // symbolic classifier
    hipLaunchKernelGGL(k_gf, dim3(256), dim3(256), 0, stream, sums, cnts, gf);
    hipLaunchKernelGGL(k_lin, dim3(BATCH, 8), dim3(64), 0, stream,
                       gf, Ws1, bs1, hs, PD, PD, PD, 1);
    hipLaunchKernelGGL(k_dot, dim3(BATCH), dim3(64), 0, stream, hs, Ws2, bs2, ys, PD);

    // fuse
    hipLaunchKernelGGL(k_final, dim3(1), dim3(128), 0, stream, yi, ys, answer, out);
}

// Round 2
// 832.277 us; speedup vs baseline: 1.6114x; 1.6114x over previous
//
#include <hip/hip_runtime.h>
#include <stdint.h>

#define N_NODES 65536
#define N_EDGES 1048576
#define BATCH   128
#define PD      512
#define CLIPD   768

typedef __attribute__((ext_vector_type(4))) float f32x4;
typedef __attribute__((ext_vector_type(4))) int   i32x4;

__device__ __forceinline__ unsigned short f2b(float f) {
    uint32_t u = __float_as_uint(f);
    return (unsigned short)((u + 0x7fffu + ((u >> 16) & 1u)) >> 16);
}
__device__ __forceinline__ float blo(uint32_t v) { return __uint_as_float(v << 16); }
__device__ __forceinline__ float bhi(uint32_t v) { return __uint_as_float(v & 0xffff0000u); }

// ---------------- Wg transpose + cast to bf16:  WgT[n][k] = bf16(Wg[k][n]) ----------------
__global__ void k_wgt(const float* __restrict__ Wg, unsigned short* __restrict__ WgT) {
    __shared__ float tile[32][33];
    int kb = blockIdx.x * 32, nb = blockIdx.y * 32;
    int tx = threadIdx.x, ty = threadIdx.y;
    tile[ty][tx] = Wg[(size_t)(kb + ty) * PD + nb + tx];
    __syncthreads();
    WgT[(size_t)(nb + ty) * PD + kb + tx] = f2b(tile[tx][ty]);
}

// ---------------- init: deg=1 (self loop), fill=0, sums=0, cnts=0 ----------------
__global__ void k_init(int* __restrict__ deg, int* __restrict__ fill,
                       float* __restrict__ sums, int* __restrict__ cnts) {
    int i = blockIdx.x * 256 + threadIdx.x;   // 65536 threads
    deg[i] = 1;
    fill[i] = 0;
    sums[i] = 0.f;                            // 128*512 == 65536
    if (i < BATCH) cnts[i] = 0;
}

// ---------------- degree count over dst ----------------
__global__ void k_deg(const int* __restrict__ ei, int* __restrict__ deg) {
    int e = blockIdx.x * 256 + threadIdx.x;   // E threads
    atomicAdd(&deg[ei[N_EDGES + e]], 1);
}

// ---------------- nodes per batch ----------------
__global__ void k_cnt(const int* __restrict__ bv, int* __restrict__ cnts) {
    int i = blockIdx.x * 256 + threadIdx.x;
    atomicAdd(&cnts[bv[i]], 1);
}

// ---------------- single-block exclusive scan of (deg-1) + dis = rsqrt(deg) ----------------
__global__ void k_scan(const int* __restrict__ deg, int* __restrict__ row_ptr,
                       float* __restrict__ dis) {
    __shared__ int part[1024];
    int t = threadIdx.x;
    const int per = N_NODES / 1024;           // 64
    int base = t * per;
    int s = 0;
    for (int i = 0; i < per; ++i) s += deg[base + i] - 1;
    part[t] = s;
    __syncthreads();
    for (int off = 1; off < 1024; off <<= 1) {
        int v = (t >= off) ? part[t - off] : 0;
        __syncthreads();
        part[t] += v;
        __syncthreads();
    }
    int excl = (t == 0) ? 0 : part[t - 1];
    for (int i = 0; i < per; ++i) {
        int d = deg[base + i];
        row_ptr[base + i] = excl;
        excl += d - 1;
        dis[base + i] = rsqrtf((float)d);
    }
    if (t == 1023) row_ptr[N_NODES] = excl;   // == E
}

// ---------------- scatter edges into CSR buckets ----------------
__global__ void k_scatter(const int* __restrict__ ei, const int* __restrict__ row_ptr,
                          int* __restrict__ fill, int* __restrict__ srcs) {
    int e = blockIdx.x * 256 + threadIdx.x;
    int d = ei[N_EDGES + e];
    int pos = row_ptr[d] + atomicAdd(&fill[d], 1);
    srcs[pos] = ei[e];
}

// ---------------- big GEMM: hn[i] = bf16( dis[i] * (x[i] @ Wg) ) ----------------
// 128x128 tile, BK=32, 4 waves; MFMA 16x16x32 bf16 via inline asm.
__device__ __forceinline__ void mfma16(f32x4& acc, i32x4 a, i32x4 b) {
    asm("v_mfma_f32_16x16x32_bf16 %0, %1, %2, %0" : "+v"(acc) : "v"(a), "v"(b));
}

__global__ __launch_bounds__(256) void k_gemm(const float* __restrict__ X,
                                              const unsigned short* __restrict__ WgT,
                                              const float* __restrict__ dis,
                                              unsigned short* __restrict__ hn) {
    __shared__ __align__(16) unsigned short As[128 * 32];
    __shared__ __align__(16) unsigned short Bs[128 * 32];
    const int m0 = blockIdx.x * 128;
    const int n0 = blockIdx.y * 128;
    const int t = threadIdx.x;
    const int lane = t & 63, w = t >> 6;
    const int wr = w >> 1, wc = w & 1;
    const int g = lane >> 4, lr = lane & 15;

    f32x4 acc[4][4] = {};

    for (int k0 = 0; k0 < PD; k0 += 32) {
        __syncthreads();
        // stage A: 128x32 f32 -> bf16, 4 floats per thread per iter, 4 iters
#pragma unroll
        for (int it = 0; it < 4; ++it) {
            int idx = it * 256 + t;
            int r = idx >> 3, kc = (idx & 7) * 4;
            float4 v = *(const float4*)&X[(size_t)(m0 + r) * PD + k0 + kc];
            uint2 o;
            o.x = (uint32_t)f2b(v.x) | ((uint32_t)f2b(v.y) << 16);
            o.y = (uint32_t)f2b(v.z) | ((uint32_t)f2b(v.w) << 16);
            *(uint2*)&As[r * 32 + kc] = o;
        }
        // stage B (already bf16): 16B per thread per iter, 2 iters
#pragma unroll
        for (int it = 0; it < 2; ++it) {
            int idx = it * 256 + t;
            int r = idx >> 2, kc = (idx & 3) * 8;
            *(uint4*)&Bs[r * 32 + kc] = *(const uint4*)&WgT[(size_t)(n0 + r) * PD + k0 + kc];
        }
        __syncthreads();

        i32x4 a[4], b[4];
#pragma unroll
        for (int i = 0; i < 4; ++i) a[i] = *(const i32x4*)&As[(wr * 64 + i * 16 + lr) * 32 + g * 8];
#pragma unroll
        for (int j = 0; j < 4; ++j) b[j] = *(const i32x4*)&Bs[(wc * 64 + j * 16 + lr) * 32 + g * 8];
#pragma unroll
        for (int i = 0; i < 4; ++i)
#pragma unroll
            for (int j = 0; j < 4; ++j) mfma16(acc[i][j], a[i], b[j]);
    }
    // MFMA->VALU read hazard padding (inline asm: compiler can't insert waits)
    asm volatile("s_nop 7\n s_nop 7\n s_nop 7\n s_nop 7");

#pragma unroll
    for (int i = 0; i < 4; ++i) {
#pragma unroll
        for (int r = 0; r < 4; ++r) {
            int row = m0 + wr * 64 + i * 16 + g * 4 + r;
            float dd = dis[row];
#pragma unroll
            for (int j = 0; j < 4; ++j) {
                int col = n0 + wc * 64 + j * 16 + lr;
                hn[(size_t)row * PD + col] = f2b(acc[i][j][r] * dd);
            }
        }
    }
}

// ---------------- aggregation + bias + relu + fused mean-pool accumulation ----------------
#define NPB 8
__global__ __launch_bounds__(256) void k_agg(const unsigned short* __restrict__ hn,
                                             const float* __restrict__ dis,
                                             const float* __restrict__ bg,
                                             const int* __restrict__ row_ptr,
                                             const int* __restrict__ srcs,
                                             const int* __restrict__ bv,
                                             float* __restrict__ sums) {
    const int t = threadIdx.x;
    const int c0 = t * 2;
    const int node0 = blockIdx.x * NPB;
    const float bg0 = bg[c0], bg1 = bg[c0 + 1];
    float s0 = 0.f, s1 = 0.f;
    int curb = bv[node0];
    for (int ni = 0; ni < NPB; ++ni) {
        int node = node0 + ni;
        int b = bv[node];
        if (b != curb) {
            atomicAdd(&sums[(size_t)curb * PD + c0], s0);
            atomicAdd(&sums[(size_t)curb * PD + c0 + 1], s1);
            s0 = s1 = 0.f;
            curb = b;
        }
        float a0 = 0.f, a1 = 0.f;
        int beg = row_ptr[node], end = row_ptr[node + 1];
        for (int e = beg; e < end; ++e) {
            int sn = srcs[e];
            uint32_t v = *(const uint32_t*)&hn[(size_t)sn * PD + c0];
            a0 += blo(v);
            a1 += bhi(v);
        }
        uint32_t v = *(const uint32_t*)&hn[(size_t)node * PD + c0];  // self loop
        a0 += blo(v);
        a1 += bhi(v);
        float dd = dis[node];
        a0 = fmaxf(fmaf(a0, dd, bg0), 0.f);
        a1 = fmaxf(fmaf(a1, dd, bg1), 0.f);
        s0 += a0;
        s1 += a1;
    }
    atomicAdd(&sums[(size_t)curb * PD + c0], s0);
    atomicAdd(&sums[(size_t)curb * PD + c0 + 1], s1);
}

// ---------------- small dense (Ncol==512 always): one block per row, 256 thr x 2 cols ----------------
__global__ __launch_bounds__(256) void k_lin(const float* __restrict__ A,
                                             const float* __restrict__ W,
                                             const float* __restrict__ bias,
                                             float* __restrict__ C,
                                             int K, int ldc, int relu) {
    const int row = blockIdx.x;
    const int c0 = threadIdx.x * 2;
    const float* a = A + (size_t)row * K;
    float acc0 = 0.f, acc1 = 0.f, acc2 = 0.f, acc3 = 0.f;
    for (int k = 0; k < K; k += 4) {
        // a[k..k+3] are block-uniform -> scalar loads; W loads coalesced float2
        float a0 = a[k], a1 = a[k + 1], a2 = a[k + 2], a3 = a[k + 3];
        float2 w0 = *(const float2*)&W[(size_t)(k + 0) * PD + c0];
        float2 w1 = *(const float2*)&W[(size_t)(k + 1) * PD + c0];
        float2 w2 = *(const float2*)&W[(size_t)(k + 2) * PD + c0];
        float2 w3 = *(const float2*)&W[(size_t)(k + 3) * PD + c0];
        acc0 = fmaf(a0, w0.x, acc0); acc1 = fmaf(a0, w0.y, acc1);
        acc2 = fmaf(a1, w1.x, acc2); acc3 = fmaf(a1, w1.y, acc3);
        acc0 = fmaf(a2, w2.x, acc0); acc1 = fmaf(a2, w2.y, acc1);
        acc2 = fmaf(a3, w3.x, acc2); acc3 = fmaf(a3, w3.y, acc3);
    }
    float r0 = acc0 + acc2 + bias[c0];
    float r1 = acc1 + acc3 + bias[c0 + 1];
    if (relu) { r0 = fmaxf(r0, 0.f); r1 = fmaxf(r1, 0.f); }
    C[(size_t)row * ldc + c0] = r0;
    C[(size_t)row * ldc + c0 + 1] = r1;
}

// ---------------- dot: y[row] = A[row][:K] @ w + b ----------------
__global__ void k_dot(const float* __restrict__ A, const float* __restrict__ w,
                      const float* __restrict__ b, float* __restrict__ y, int K) {
    int row = blockIdx.x;
    int t = threadIdx.x;   // 64
    float s = 0.f;
    for (int k = t; k < K; k += 64) s = fmaf(A[(size_t)row * K + k], w[k], s);
    for (int off = 32; off; off >>= 1) s += __shfl_down(s, off);
    if (t == 0) y[row] = s + b[0];
}

// ---------------- graph features: gf = sums / max(cnts,1) ----------------
__global__ void k_gf(const float* __restrict__ sums, const int* __restrict__ cnts,
                     float* __restrict__ gf) {
    int i = blockIdx.x * 256 + threadIdx.x;   // 65536
    float c = fmaxf((float)cnts[i >> 9], 1.f);
    gf[i] = sums[i] / c;
}

// ---------------- logits + BCE loss ----------------
__global__ void k_final(const float* __restrict__ yi, const float* __restrict__ ys,
                        const float* __restrict__ ans, float* __restrict__ out) {
    __shared__ float red[128];
    int t = threadIdx.x;   // 128
    float l = fmaxf(yi[t], ys[t]);
    out[t] = l;
    float li = fmaxf(l, 0.f) + log1pf(expf(-fabsf(l))) - l * ans[t];
    red[t] = li;
    __syncthreads();
    for (int off = 64; off; off >>= 1) {
        if (t < off) red[t] += red[t + off];
        __syncthreads();
    }
    if (t == 0) out[BATCH] = red[0] / (float)BATCH;
}

extern "C" void kernel_launch(void* const* d_in, const int* in_sizes, int n_in,
                              void* d_out, int out_size, void* d_ws, size_t ws_size,
                              hipStream_t stream) {
    const float* image_features = (const float*)d_in[0];
    const float* text_features  = (const float*)d_in[1];
    const float* answer         = (const float*)d_in[2];
    const float* x_nodes        = (const float*)d_in[3];
    const int*   edge_index     = (const int*)d_in[4];
    const int*   batch_vec      = (const int*)d_in[5];
    const float* W_img = (const float*)d_in[6];
    const float* b_img = (const float*)d_in[7];
    const float* W_txt = (const float*)d_in[8];
    const float* b_txt = (const float*)d_in[9];
    const float* W1  = (const float*)d_in[10];
    const float* b1  = (const float*)d_in[11];
    const float* W2  = (const float*)d_in[12];
    const float* b2  = (const float*)d_in[13];
    const float* Wg  = (const float*)d_in[14];
    const float* bg  = (const float*)d_in[15];
    const float* Ws1 = (const float*)d_in[16];
    const float* bs1 = (const float*)d_in[17];
    const float* Ws2 = (const float*)d_in[18];
    const float* bs2 = (const float*)d_in[19];
    float* out = (float*)d_out;

    char* base = (char*)d_ws;
    size_t cur = 0;
    auto alloc = [&](size_t bytes) -> void* {
        void* r = base + cur;
        cur = (cur + bytes + 255) & ~(size_t)255;
        return r;
    };
    unsigned short* WgT = (unsigned short*)alloc((size_t)PD * PD * 2);
    unsigned short* hn  = (unsigned short*)alloc((size_t)N_NODES * PD * 2);
    int*   deg     = (int*)alloc((size_t)N_NODES * 4);
    float* dis     = (float*)alloc((size_t)N_NODES * 4);
    int*   row_ptr = (int*)alloc((size_t)(N_NODES + 1) * 4);
    int*   fill    = (int*)alloc((size_t)N_NODES * 4);
    int*   srcs    = (int*)alloc((size_t)N_EDGES * 4);
    float* sums    = (float*)alloc((size_t)BATCH * PD * 4);
    int*   cnts    = (int*)alloc((size_t)BATCH * 4);
    float* combined = (float*)alloc((size_t)BATCH * 1024 * 4);
    float* h1      = (float*)alloc((size_t)BATCH * PD * 4);
    float* gf      = (float*)alloc((size_t)BATCH * PD * 4);
    float* hs      = (float*)alloc((size_t)BATCH * PD * 4);
    float* yi      = (float*)alloc((size_t)BATCH * 4);
    float* ys      = (float*)alloc((size_t)BATCH * 4);

    // symbolic-branch preprocessing
    hipLaunchKernelGGL(k_wgt, dim3(16, 16), dim3(32, 32), 0, stream, Wg, WgT);
    hipLaunchKernelGGL(k_init, dim3(256), dim3(256), 0, stream, deg, fill, sums, cnts);
    hipLaunchKernelGGL(k_deg, dim3(4096), dim3(256), 0, stream, edge_index, deg);
    hipLaunchKernelGGL(k_cnt, dim3(256), dim3(256), 0, stream, batch_vec, cnts);
    hipLaunchKernelGGL(k_scan, dim3(1), dim3(1024), 0, stream, deg, row_ptr, dis);
    hipLaunchKernelGGL(k_scatter, dim3(4096), dim3(256), 0, stream, edge_index, row_ptr, fill, srcs);
    hipLaunchKernelGGL(k_gemm, dim3(N_NODES / 128, PD / 128), dim3(256), 0, stream,
                       x_nodes, WgT, dis, hn);
    hipLaunchKernelGGL(k_agg, dim3(N_NODES / NPB), dim3(256), 0, stream,
                       hn, dis, bg, row_ptr, srcs, batch_vec, sums);

    // implicit branch
    hipLaunchKernelGGL(k_lin, dim3(BATCH), dim3(256), 0, stream,
                       image_features, W_img, b_img, combined, CLIPD, 1024, 0);
    hipLaunchKernelGGL(k_lin, dim3(BATCH), dim3(256), 0, stream,
                       text_features, W_txt, b_txt, combined + PD, CLIPD, 1024, 0);
    hipLaunchKernelGGL(k_lin, dim3(BATCH), dim3(256), 0, stream,
                       combined, W1, b1, h1, 1024, PD, 1);
    hipLaunchKernelGGL(k_dot, dim3(BATCH), dim3(64), 0, stream, h1, W2, b2, yi, PD);

    // symbolic classifier
    hipLaunchKernelGGL(k_gf, dim3(256), dim3(256), 0, stream, sums, cnts, gf);
    hipLaunchKernelGGL(k_lin, dim3(BATCH), dim3(256), 0, stream,
                       gf, Ws1, bs1, hs, PD, PD, 1);
    hipLaunchKernelGGL(k_dot, dim3(BATCH), dim3(64), 0, stream, hs, Ws2, bs2, ys, PD);

    // fuse
    hipLaunchKernelGGL(k_final, dim3(1), dim3(128), 0, stream, yi, ys, answer, out);
}

// Round 3
// 827.182 us; speedup vs baseline: 1.6213x; 1.0062x over previous
//
#include <hip/hip_runtime.h>
#include <stdint.h>

#define N_NODES 65536
#define N_EDGES 1048576
#define BATCH   128
#define PD      512
#define CLIPD   768

typedef __attribute__((ext_vector_type(4))) float f32x4;
typedef __attribute__((ext_vector_type(4))) int   i32x4;

__device__ __forceinline__ unsigned short f2b(float f) {
    uint32_t u = __float_as_uint(f);
    return (unsigned short)((u + 0x7fffu + ((u >> 16) & 1u)) >> 16);
}
__device__ __forceinline__ float blo(uint32_t v) { return __uint_as_float(v << 16); }
__device__ __forceinline__ float bhi(uint32_t v) { return __uint_as_float(v & 0xffff0000u); }

__device__ __forceinline__ void gl_lds16(const unsigned short* g, unsigned short* l) {
    __builtin_amdgcn_global_load_lds((const __attribute__((address_space(1))) void*)g,
                                     (__attribute__((address_space(3))) void*)l, 16, 0, 0);
}

// ---------------- Wg transpose + cast to bf16; also zero cnts ----------------
__global__ void k_wgt(const float* __restrict__ Wg, unsigned short* __restrict__ WgT,
                      int* __restrict__ cnts) {
    __shared__ float tile[32][33];
    int kb = blockIdx.x * 32, nb = blockIdx.y * 32;
    int tx = threadIdx.x, ty = threadIdx.y;
    if (kb == 0 && nb == 0 && ty < 4) cnts[ty * 32 + tx] = 0;
    tile[ty][tx] = Wg[(size_t)(kb + ty) * PD + nb + tx];
    __syncthreads();
    WgT[(size_t)(nb + ty) * PD + kb + tx] = f2b(tile[tx][ty]);
}

// ---------------- init: deg=1, fill=0, sums=0, batch-count atomic ----------------
__global__ void k_init(int* __restrict__ deg, int* __restrict__ fill,
                       float* __restrict__ sums, const int* __restrict__ bv,
                       int* __restrict__ cnts) {
    int i = blockIdx.x * 256 + threadIdx.x;   // 65536 threads
    deg[i] = 1;
    fill[i] = 0;
    sums[i] = 0.f;                            // 128*512 == 65536
    atomicAdd(&cnts[bv[i]], 1);
}

// ---------------- degree count over dst ----------------
__global__ void k_deg(const int* __restrict__ ei, int* __restrict__ deg) {
    int e = blockIdx.x * 256 + threadIdx.x;   // E threads
    atomicAdd(&deg[ei[N_EDGES + e]], 1);
}

// ---------------- single-block exclusive scan of (deg-1) + dis = rsqrt(deg) ----------------
__global__ void k_scan(const int* __restrict__ deg, int* __restrict__ row_ptr,
                       float* __restrict__ dis) {
    __shared__ int part[1024];
    int t = threadIdx.x;
    const int per = N_NODES / 1024;           // 64
    int base = t * per;
    int s = 0;
    for (int i = 0; i < per; ++i) s += deg[base + i] - 1;
    part[t] = s;
    __syncthreads();
    for (int off = 1; off < 1024; off <<= 1) {
        int v = (t >= off) ? part[t - off] : 0;
        __syncthreads();
        part[t] += v;
        __syncthreads();
    }
    int excl = (t == 0) ? 0 : part[t - 1];
    for (int i = 0; i < per; ++i) {
        int d = deg[base + i];
        row_ptr[base + i] = excl;
        excl += d - 1;
        dis[base + i] = rsqrtf((float)d);
    }
    if (t == 1023) row_ptr[N_NODES] = excl;   // == E
}

// ---------------- scatter edges into CSR buckets ----------------
__global__ void k_scatter(const int* __restrict__ ei, const int* __restrict__ row_ptr,
                          int* __restrict__ fill, int* __restrict__ srcs) {
    int e = blockIdx.x * 256 + threadIdx.x;
    int d = ei[N_EDGES + e];
    int pos = row_ptr[d] + atomicAdd(&fill[d], 1);
    srcs[pos] = ei[e];
}

// ---------------- X f32 -> bf16 ----------------
__global__ void k_cast(const float* __restrict__ X, unsigned short* __restrict__ X16) {
    size_t i = (size_t)(blockIdx.x * 256 + threadIdx.x) * 8;
    float4 v0 = *(const float4*)&X[i];
    float4 v1 = *(const float4*)&X[i + 4];
    uint4 o;
    o.x = (uint32_t)f2b(v0.x) | ((uint32_t)f2b(v0.y) << 16);
    o.y = (uint32_t)f2b(v0.z) | ((uint32_t)f2b(v0.w) << 16);
    o.z = (uint32_t)f2b(v1.x) | ((uint32_t)f2b(v1.y) << 16);
    o.w = (uint32_t)f2b(v1.z) | ((uint32_t)f2b(v1.w) << 16);
    *(uint4*)&X16[i] = o;
}

// ---------------- big GEMM: hn[i] = bf16( dis[i] * (x[i] @ Wg) ) ----------------
// 128x128 tile, BK=32, 4 waves; A,B staged via global_load_lds (16B).
__device__ __forceinline__ void mfma16(f32x4& acc, i32x4 a, i32x4 b) {
    asm("v_mfma_f32_16x16x32_bf16 %0, %1, %2, %0" : "+v"(acc) : "v"(a), "v"(b));
}

__global__ __launch_bounds__(256) void k_gemm(const unsigned short* __restrict__ X16,
                                              const unsigned short* __restrict__ WgT,
                                              const float* __restrict__ dis,
                                              unsigned short* __restrict__ hn) {
    __shared__ __align__(16) unsigned short As[128 * 32];
    __shared__ __align__(16) unsigned short Bs[128 * 32];
    const int m0 = blockIdx.x * 128;
    const int n0 = blockIdx.y * 128;
    const int t = threadIdx.x;
    const int lane = t & 63, w = t >> 6;
    const int wr = w >> 1, wc = w & 1;
    const int g = lane >> 4, lr = lane & 15;

    f32x4 acc[4][4] = {};

    for (int k0 = 0; k0 < PD; k0 += 32) {
        __syncthreads();
#pragma unroll
        for (int it = 0; it < 2; ++it) {
            int idx = it * 256 + t;
            int r = idx >> 2, c8 = (idx & 3) * 8;
            gl_lds16(&X16[(size_t)(m0 + r) * PD + k0 + c8], &As[idx * 8]);
            gl_lds16(&WgT[(size_t)(n0 + r) * PD + k0 + c8], &Bs[idx * 8]);
        }
        __syncthreads();   // vmcnt(0) drained by compiler before barrier

        i32x4 a[4], b[4];
#pragma unroll
        for (int i = 0; i < 4; ++i) a[i] = *(const i32x4*)&As[(wr * 64 + i * 16 + lr) * 32 + g * 8];
#pragma unroll
        for (int j = 0; j < 4; ++j) b[j] = *(const i32x4*)&Bs[(wc * 64 + j * 16 + lr) * 32 + g * 8];
#pragma unroll
        for (int i = 0; i < 4; ++i)
#pragma unroll
            for (int j = 0; j < 4; ++j) mfma16(acc[i][j], a[i], b[j]);
    }
    // MFMA->VALU read hazard padding (inline asm: compiler can't insert waits)
    asm volatile("s_nop 7\n s_nop 7\n s_nop 7\n s_nop 7");

#pragma unroll
    for (int i = 0; i < 4; ++i) {
#pragma unroll
        for (int r = 0; r < 4; ++r) {
            int row = m0 + wr * 64 + i * 16 + g * 4 + r;
            float dd = dis[row];
#pragma unroll
            for (int j = 0; j < 4; ++j) {
                int col = n0 + wc * 64 + j * 16 + lr;
                hn[(size_t)row * PD + col] = f2b(acc[i][j][r] * dd);
            }
        }
    }
}

// ---------------- aggregation + bias + relu + fused mean-pool accumulation ----------------
#define NPB 8
__global__ __launch_bounds__(256) void k_agg(const unsigned short* __restrict__ hn,
                                             const float* __restrict__ dis,
                                             const float* __restrict__ bg,
                                             const int* __restrict__ row_ptr,
                                             const int* __restrict__ srcs,
                                             const int* __restrict__ bv,
                                             float* __restrict__ sums) {
    const int t = threadIdx.x;
    const int c0 = t * 2;
    const int node0 = blockIdx.x * NPB;
    const float bg0 = bg[c0], bg1 = bg[c0 + 1];
    float s0 = 0.f, s1 = 0.f;
    int curb = bv[node0];
    for (int ni = 0; ni < NPB; ++ni) {
        int node = node0 + ni;
        int b = bv[node];
        if (b != curb) {
            atomicAdd(&sums[(size_t)curb * PD + c0], s0);
            atomicAdd(&sums[(size_t)curb * PD + c0 + 1], s1);
            s0 = s1 = 0.f;
            curb = b;
        }
        float a0 = 0.f, a1 = 0.f;
        int beg = row_ptr[node], end = row_ptr[node + 1];
        int e = beg;
        // 4-wide unroll: 4 independent gathers in flight per wait
        for (; e + 4 <= end; e += 4) {
            int sn0 = srcs[e], sn1 = srcs[e + 1], sn2 = srcs[e + 2], sn3 = srcs[e + 3];
            uint32_t v0 = *(const uint32_t*)&hn[(size_t)sn0 * PD + c0];
            uint32_t v1 = *(const uint32_t*)&hn[(size_t)sn1 * PD + c0];
            uint32_t v2 = *(const uint32_t*)&hn[(size_t)sn2 * PD + c0];
            uint32_t v3 = *(const uint32_t*)&hn[(size_t)sn3 * PD + c0];
            a0 += (blo(v0) + blo(v1)) + (blo(v2) + blo(v3));
            a1 += (bhi(v0) + bhi(v1)) + (bhi(v2) + bhi(v3));
        }
        for (; e < end; ++e) {
            int sn = srcs[e];
            uint32_t v = *(const uint32_t*)&hn[(size_t)sn * PD + c0];
            a0 += blo(v);
            a1 += bhi(v);
        }
        uint32_t v = *(const uint32_t*)&hn[(size_t)node * PD + c0];  // self loop
        a0 += blo(v);
        a1 += bhi(v);
        float dd = dis[node];
        a0 = fmaxf(fmaf(a0, dd, bg0), 0.f);
        a1 = fmaxf(fmaf(a1, dd, bg1), 0.f);
        s0 += a0;
        s1 += a1;
    }
    atomicAdd(&sums[(size_t)curb * PD + c0], s0);
    atomicAdd(&sums[(size_t)curb * PD + c0 + 1], s1);
}

// ---------------- small dense (Ncol==512): one block per row, 256 thr x 2 cols ----------------
// optional cnts: result scaled by 1/max(cnt,1) before bias (mean-pool folding)
__global__ __launch_bounds__(256) void k_lin(const float* __restrict__ A,
                                             const float* __restrict__ W,
                                             const float* __restrict__ bias,
                                             float* __restrict__ C,
                                             int K, int ldc, int relu,
                                             const int* __restrict__ cnts) {
    const int row = blockIdx.x;
    const int c0 = threadIdx.x * 2;
    const float* a = A + (size_t)row * K;
    float acc0 = 0.f, acc1 = 0.f, acc2 = 0.f, acc3 = 0.f;
    for (int k = 0; k < K; k += 4) {
        float a0 = a[k], a1 = a[k + 1], a2 = a[k + 2], a3 = a[k + 3];
        float2 w0 = *(const float2*)&W[(size_t)(k + 0) * PD + c0];
        float2 w1 = *(const float2*)&W[(size_t)(k + 1) * PD + c0];
        float2 w2 = *(const float2*)&W[(size_t)(k + 2) * PD + c0];
        float2 w3 = *(const float2*)&W[(size_t)(k + 3) * PD + c0];
        acc0 = fmaf(a0, w0.x, acc0); acc1 = fmaf(a0, w0.y, acc1);
        acc2 = fmaf(a1, w1.x, acc2); acc3 = fmaf(a1, w1.y, acc3);
        acc0 = fmaf(a2, w2.x, acc0); acc1 = fmaf(a2, w2.y, acc1);
        acc2 = fmaf(a3, w3.x, acc2); acc3 = fmaf(a3, w3.y, acc3);
    }
    float s = 1.f;
    if (cnts) s = 1.f / fmaxf((float)cnts[row], 1.f);
    float r0 = fmaf(acc0 + acc2, s, bias[c0]);
    float r1 = fmaf(acc1 + acc3, s, bias[c0 + 1]);
    if (relu) { r0 = fmaxf(r0, 0.f); r1 = fmaxf(r1, 0.f); }
    C[(size_t)row * ldc + c0] = r0;
    C[(size_t)row * ldc + c0 + 1] = r1;
}

// ---------------- dot: y[row] = A[row][:K] @ w + b ----------------
__global__ void k_dot(const float* __restrict__ A, const float* __restrict__ w,
                      const float* __restrict__ b, float* __restrict__ y, int K) {
    int row = blockIdx.x;
    int t = threadIdx.x;   // 64
    float s = 0.f;
    for (int k = t; k < K; k += 64) s = fmaf(A[(size_t)row * K + k], w[k], s);
    for (int off = 32; off; off >>= 1) s += __shfl_down(s, off);
    if (t == 0) y[row] = s + b[0];
}

// ---------------- logits + BCE loss ----------------
__global__ void k_final(const float* __restrict__ yi, const float* __restrict__ ys,
                        const float* __restrict__ ans, float* __restrict__ out) {
    __shared__ float red[128];
    int t = threadIdx.x;   // 128
    float l = fmaxf(yi[t], ys[t]);
    out[t] = l;
    float li = fmaxf(l, 0.f) + log1pf(expf(-fabsf(l))) - l * ans[t];
    red[t] = li;
    __syncthreads();
    for (int off = 64; off; off >>= 1) {
        if (t < off) red[t] += red[t + off];
        __syncthreads();
    }
    if (t == 0) out[BATCH] = red[0] / (float)BATCH;
}

extern "C" void kernel_launch(void* const* d_in, const int* in_sizes, int n_in,
                              void* d_out, int out_size, void* d_ws, size_t ws_size,
                              hipStream_t stream) {
    const float* image_features = (const float*)d_in[0];
    const float* text_features  = (const float*)d_in[1];
    const float* answer         = (const float*)d_in[2];
    const float* x_nodes        = (const float*)d_in[3];
    const int*   edge_index     = (const int*)d_in[4];
    const int*   batch_vec      = (const int*)d_in[5];
    const float* W_img = (const float*)d_in[6];
    const float* b_img = (const float*)d_in[7];
    const float* W_txt = (const float*)d_in[8];
    const float* b_txt = (const float*)d_in[9];
    const float* W1  = (const float*)d_in[10];
    const float* b1  = (const float*)d_in[11];
    const float* W2  = (const float*)d_in[12];
    const float* b2  = (const float*)d_in[13];
    const float* Wg  = (const float*)d_in[14];
    const float* bg  = (const float*)d_in[15];
    const float* Ws1 = (const float*)d_in[16];
    const float* bs1 = (const float*)d_in[17];
    const float* Ws2 = (const float*)d_in[18];
    const float* bs2 = (const float*)d_in[19];
    float* out = (float*)d_out;

    char* base = (char*)d_ws;
    size_t cur = 0;
    auto alloc = [&](size_t bytes) -> void* {
        void* r = base + cur;
        cur = (cur + bytes + 255) & ~(size_t)255;
        return r;
    };
    unsigned short* WgT = (unsigned short*)alloc((size_t)PD * PD * 2);
    unsigned short* X16 = (unsigned short*)alloc((size_t)N_NODES * PD * 2);
    unsigned short* hn  = (unsigned short*)alloc((size_t)N_NODES * PD * 2);
    int*   deg     = (int*)alloc((size_t)N_NODES * 4);
    float* dis     = (float*)alloc((size_t)N_NODES * 4);
    int*   row_ptr = (int*)alloc((size_t)(N_NODES + 1) * 4);
    int*   fill    = (int*)alloc((size_t)N_NODES * 4);
    int*   srcs    = (int*)alloc((size_t)N_EDGES * 4);
    float* sums    = (float*)alloc((size_t)BATCH * PD * 4);
    int*   cnts    = (int*)alloc((size_t)BATCH * 4);
    float* combined = (float*)alloc((size_t)BATCH * 1024 * 4);
    float* h1      = (float*)alloc((size_t)BATCH * PD * 4);
    float* hs      = (float*)alloc((size_t)BATCH * PD * 4);
    float* yi      = (float*)alloc((size_t)BATCH * 4);
    float* ys      = (float*)alloc((size_t)BATCH * 4);

    // symbolic-branch preprocessing
    hipLaunchKernelGGL(k_wgt, dim3(16, 16), dim3(32, 32), 0, stream, Wg, WgT, cnts);
    hipLaunchKernelGGL(k_init, dim3(256), dim3(256), 0, stream, deg, fill, sums, batch_vec, cnts);
    hipLaunchKernelGGL(k_deg, dim3(4096), dim3(256), 0, stream, edge_index, deg);
    hipLaunchKernelGGL(k_scan, dim3(1), dim3(1024), 0, stream, deg, row_ptr, dis);
    hipLaunchKernelGGL(k_scatter, dim3(4096), dim3(256), 0, stream, edge_index, row_ptr, fill, srcs);
    hipLaunchKernelGGL(k_cast, dim3(16384), dim3(256), 0, stream, x_nodes, X16);
    hipLaunchKernelGGL(k_gemm, dim3(N_NODES / 128, PD / 128), dim3(256), 0, stream,
                       X16, WgT, dis, hn);
    hipLaunchKernelGGL(k_agg, dim3(N_NODES / NPB), dim3(256), 0, stream,
                       hn, dis, bg, row_ptr, srcs, batch_vec, sums);

    // implicit branch
    hipLaunchKernelGGL(k_lin, dim3(BATCH), dim3(256), 0, stream,
                       image_features, W_img, b_img, combined, CLIPD, 1024, 0, (const int*)nullptr);
    hipLaunchKernelGGL(k_lin, dim3(BATCH), dim3(256), 0, stream,
                       text_features, W_txt, b_txt, combined + PD, CLIPD, 1024, 0, (const int*)nullptr);
    hipLaunchKernelGGL(k_lin, dim3(BATCH), dim3(256), 0, stream,
                       combined, W1, b1, h1, 1024, PD, 1, (const int*)nullptr);
    hipLaunchKernelGGL(k_dot, dim3(BATCH), dim3(64), 0, stream, h1, W2, b2, yi, PD);

    // symbolic classifier (mean-pool folded in via cnts)
    hipLaunchKernelGGL(k_lin, dim3(BATCH), dim3(256), 0, stream,
                       sums, Ws1, bs1, hs, PD, PD, 1, cnts);
    hipLaunchKernelGGL(k_dot, dim3(BATCH), dim3(64), 0, stream, hs, Ws2, bs2, ys, PD);

    // fuse
    hipLaunchKernelGGL(k_final, dim3(1), dim3(128), 0, stream, yi, ys, answer, out);
}

// Round 4
// 621.802 us; speedup vs baseline: 2.1568x; 1.3303x over previous
//
#include <hip/hip_runtime.h>
#include <stdint.h>

#define N_NODES 65536
#define N_EDGES 1048576
#define BATCH   128
#define PD      512
#define CLIPD   768

typedef __attribute__((ext_vector_type(4))) float f32x4;
typedef __attribute__((ext_vector_type(4))) int   i32x4;

__device__ __forceinline__ unsigned short f2b(float f) {
    uint32_t u = __float_as_uint(f);
    return (unsigned short)((u + 0x7fffu + ((u >> 16) & 1u)) >> 16);
}
__device__ __forceinline__ float blo(uint32_t v) { return __uint_as_float(v << 16); }
__device__ __forceinline__ float bhi(uint32_t v) { return __uint_as_float(v & 0xffff0000u); }

// ---------------- Wg transpose+cast to bf16; batch counts via binary search on sorted bv ----------------
__global__ void k_wgt(const float* __restrict__ Wg, unsigned short* __restrict__ WgT,
                      const int* __restrict__ bv, int* __restrict__ cnts) {
    __shared__ float tile[32][33];
    int kb = blockIdx.x * 32, nb = blockIdx.y * 32;
    int tx = threadIdx.x, ty = threadIdx.y;
    if (kb == 0 && nb == 0) {
        int tid = ty * 32 + tx;
        if (tid < BATCH) {
            int lo = 0, hi = N_NODES;
            while (lo < hi) { int m = (lo + hi) >> 1; if (bv[m] < tid) lo = m + 1; else hi = m; }
            int lo2 = lo, hi2 = N_NODES;
            while (lo2 < hi2) { int m = (lo2 + hi2) >> 1; if (bv[m] < tid + 1) lo2 = m + 1; else hi2 = m; }
            cnts[tid] = lo2 - lo;
        }
    }
    tile[ty][tx] = Wg[(size_t)(kb + ty) * PD + nb + tx];
    __syncthreads();
    WgT[(size_t)(nb + ty) * PD + kb + tx] = f2b(tile[tx][ty]);
}

// ---------------- init: deg=1 (self loop), fill=0, sums=0 ----------------
__global__ void k_init(int* __restrict__ deg, int* __restrict__ fill,
                       float* __restrict__ sums) {
    int i = blockIdx.x * 256 + threadIdx.x;   // 65536 threads
    deg[i] = 1;
    fill[i] = 0;
    sums[i] = 0.f;                            // 128*512 == 65536
}

// ---------------- degree count over dst ----------------
__global__ void k_deg(const int* __restrict__ ei, int* __restrict__ deg) {
    int e = blockIdx.x * 256 + threadIdx.x;   // E threads
    atomicAdd(&deg[ei[N_EDGES + e]], 1);
}

// ---------------- coalesced wave-scan: row_ptr = exclusive scan of (deg-1); dis = rsqrt(deg) ----------------
__global__ void k_scan(const int* __restrict__ deg, int* __restrict__ row_ptr,
                       float* __restrict__ dis) {
    __shared__ int wsum[16];
    const int t = threadIdx.x;            // 1024
    const int w = t >> 6, l = t & 63;
    const int base = w * 4096;            // contiguous region per wave
    // phase 1: region total of (deg-1), coalesced loads
    int s = 0;
    for (int i = 0; i < 64; ++i) s += deg[base + i * 64 + l];
    s -= 64;
#pragma unroll
    for (int off = 1; off < 64; off <<= 1) s += __shfl_xor(s, off);
    if (l == 0) wsum[w] = s;
    __syncthreads();
    // phase 2: exclusive prefix over the 16 wave totals
    int carry = 0;
    for (int i = 0; i < 16; ++i) carry += (i < w) ? wsum[i] : 0;
    // phase 3: coalesced walk with wave-inclusive scan + prefetch
    int idx = base + l;
    int d = deg[idx];
    for (int i = 0; i < 64; ++i) {
        int dn = 0;
        if (i < 63) dn = deg[idx + 64];
        int v = d - 1;
        int inc = v;
#pragma unroll
        for (int off = 1; off < 64; off <<= 1) {
            int n = __shfl_up(inc, off);
            if (l >= off) inc += n;
        }
        row_ptr[idx] = carry + inc - v;
        dis[idx] = rsqrtf((float)d);
        carry += __shfl(inc, 63);
        idx += 64;
        d = dn;
    }
    if (t == 1023) row_ptr[N_NODES] = carry;  // == E
}

// ---------------- scatter edges into CSR buckets ----------------
__global__ void k_scatter(const int* __restrict__ ei, const int* __restrict__ row_ptr,
                          int* __restrict__ fill, int* __restrict__ srcs) {
    int e = blockIdx.x * 256 + threadIdx.x;
    int d = ei[N_EDGES + e];
    int pos = row_ptr[d] + atomicAdd(&fill[d], 1);
    srcs[pos] = ei[e];
}

// ---------------- big GEMM: hn[i] = bf16( dis[i] * (x[i] @ Wg) ) ----------------
// 128x128 tile, BK=32, 4 waves; reg-staged f32 A (cast in-kernel), bf16 B. (round-2 form, measured faster)
__device__ __forceinline__ void mfma16(f32x4& acc, i32x4 a, i32x4 b) {
    asm("v_mfma_f32_16x16x32_bf16 %0, %1, %2, %0" : "+v"(acc) : "v"(a), "v"(b));
}

__global__ __launch_bounds__(256) void k_gemm(const float* __restrict__ X,
                                              const unsigned short* __restrict__ WgT,
                                              const float* __restrict__ dis,
                                              unsigned short* __restrict__ hn) {
    __shared__ __align__(16) unsigned short As[128 * 32];
    __shared__ __align__(16) unsigned short Bs[128 * 32];
    const int m0 = blockIdx.x * 128;
    const int n0 = blockIdx.y * 128;
    const int t = threadIdx.x;
    const int lane = t & 63, w = t >> 6;
    const int wr = w >> 1, wc = w & 1;
    const int g = lane >> 4, lr = lane & 15;

    f32x4 acc[4][4] = {};

    for (int k0 = 0; k0 < PD; k0 += 32) {
        __syncthreads();
#pragma unroll
        for (int it = 0; it < 4; ++it) {
            int idx = it * 256 + t;
            int r = idx >> 3, kc = (idx & 7) * 4;
            float4 v = *(const float4*)&X[(size_t)(m0 + r) * PD + k0 + kc];
            uint2 o;
            o.x = (uint32_t)f2b(v.x) | ((uint32_t)f2b(v.y) << 16);
            o.y = (uint32_t)f2b(v.z) | ((uint32_t)f2b(v.w) << 16);
            *(uint2*)&As[r * 32 + kc] = o;
        }
#pragma unroll
        for (int it = 0; it < 2; ++it) {
            int idx = it * 256 + t;
            int r = idx >> 2, kc = (idx & 3) * 8;
            *(uint4*)&Bs[r * 32 + kc] = *(const uint4*)&WgT[(size_t)(n0 + r) * PD + k0 + kc];
        }
        __syncthreads();

        i32x4 a[4], b[4];
#pragma unroll
        for (int i = 0; i < 4; ++i) a[i] = *(const i32x4*)&As[(wr * 64 + i * 16 + lr) * 32 + g * 8];
#pragma unroll
        for (int j = 0; j < 4; ++j) b[j] = *(const i32x4*)&Bs[(wc * 64 + j * 16 + lr) * 32 + g * 8];
#pragma unroll
        for (int i = 0; i < 4; ++i)
#pragma unroll
            for (int j = 0; j < 4; ++j) mfma16(acc[i][j], a[i], b[j]);
    }
    asm volatile("s_nop 7\n s_nop 7\n s_nop 7\n s_nop 7");

#pragma unroll
    for (int i = 0; i < 4; ++i) {
#pragma unroll
        for (int r = 0; r < 4; ++r) {
            int row = m0 + wr * 64 + i * 16 + g * 4 + r;
            float dd = dis[row];
#pragma unroll
            for (int j = 0; j < 4; ++j) {
                int col = n0 + wc * 64 + j * 16 + lr;
                hn[(size_t)row * PD + col] = f2b(acc[i][j][r] * dd);
            }
        }
    }
}

// ---------------- aggregation + bias + relu + fused mean-pool accumulation ----------------
// 2 wave-aligned groups of 128 threads; 4 cols (8B) per thread; 4-edge MLP unroll.
#define NPB 16
__global__ __launch_bounds__(256) void k_agg(const unsigned short* __restrict__ hn,
                                             const float* __restrict__ dis,
                                             const float* __restrict__ bg,
                                             const int* __restrict__ row_ptr,
                                             const int* __restrict__ srcs,
                                             const int* __restrict__ bv,
                                             float* __restrict__ sums) {
    const int t = threadIdx.x;
    const int grp = t >> 7;          // group 0: nodes +0,+2,.. ; group 1: +1,+3,..
    const int tl = t & 127;
    const int c0 = tl * 4;
    const int node0 = blockIdx.x * NPB + grp;
    const float bg0 = bg[c0], bg1 = bg[c0 + 1], bg2 = bg[c0 + 2], bg3 = bg[c0 + 3];
    float s0 = 0.f, s1 = 0.f, s2 = 0.f, s3 = 0.f;
    int curb = bv[node0];
    for (int ni = 0; ni < NPB; ni += 2) {
        int node = node0 + ni;
        int b = bv[node];
        if (b != curb) {
            atomicAdd(&sums[(size_t)curb * PD + c0 + 0], s0);
            atomicAdd(&sums[(size_t)curb * PD + c0 + 1], s1);
            atomicAdd(&sums[(size_t)curb * PD + c0 + 2], s2);
            atomicAdd(&sums[(size_t)curb * PD + c0 + 3], s3);
            s0 = s1 = s2 = s3 = 0.f;
            curb = b;
        }
        float a0 = 0.f, a1 = 0.f, a2 = 0.f, a3 = 0.f;
        int beg = row_ptr[node], end = row_ptr[node + 1];
        int e = beg;
        for (; e + 4 <= end; e += 4) {
            int sn0 = srcs[e], sn1 = srcs[e + 1], sn2 = srcs[e + 2], sn3 = srcs[e + 3];
            uint2 v0 = *(const uint2*)&hn[(size_t)sn0 * PD + c0];
            uint2 v1 = *(const uint2*)&hn[(size_t)sn1 * PD + c0];
            uint2 v2 = *(const uint2*)&hn[(size_t)sn2 * PD + c0];
            uint2 v3 = *(const uint2*)&hn[(size_t)sn3 * PD + c0];
            a0 += (blo(v0.x) + blo(v1.x)) + (blo(v2.x) + blo(v3.x));
            a1 += (bhi(v0.x) + bhi(v1.x)) + (bhi(v2.x) + bhi(v3.x));
            a2 += (blo(v0.y) + blo(v1.y)) + (blo(v2.y) + blo(v3.y));
            a3 += (bhi(v0.y) + bhi(v1.y)) + (bhi(v2.y) + bhi(v3.y));
        }
        for (; e < end; ++e) {
            int sn = srcs[e];
            uint2 v = *(const uint2*)&hn[(size_t)sn * PD + c0];
            a0 += blo(v.x); a1 += bhi(v.x); a2 += blo(v.y); a3 += bhi(v.y);
        }
        uint2 v = *(const uint2*)&hn[(size_t)node * PD + c0];  // self loop
        a0 += blo(v.x); a1 += bhi(v.x); a2 += blo(v.y); a3 += bhi(v.y);
        float dd = dis[node];
        a0 = fmaxf(fmaf(a0, dd, bg0), 0.f);
        a1 = fmaxf(fmaf(a1, dd, bg1), 0.f);
        a2 = fmaxf(fmaf(a2, dd, bg2), 0.f);
        a3 = fmaxf(fmaf(a3, dd, bg3), 0.f);
        s0 += a0; s1 += a1; s2 += a2; s3 += a3;
    }
    atomicAdd(&sums[(size_t)curb * PD + c0 + 0], s0);
    atomicAdd(&sums[(size_t)curb * PD + c0 + 1], s1);
    atomicAdd(&sums[(size_t)curb * PD + c0 + 2], s2);
    atomicAdd(&sums[(size_t)curb * PD + c0 + 3], s3);
}

// ---------------- small dense (Ncol==512): one block per row, 256 thr x 2 cols ----------------
__global__ __launch_bounds__(256) void k_lin(const float* __restrict__ A,
                                             const float* __restrict__ W,
                                             const float* __restrict__ bias,
                                             float* __restrict__ C,
                                             int K, int ldc, int relu,
                                             const int* __restrict__ cnts) {
    const int row = blockIdx.x;
    const int c0 = threadIdx.x * 2;
    const float* a = A + (size_t)row * K;
    float acc0 = 0.f, acc1 = 0.f, acc2 = 0.f, acc3 = 0.f;
    for (int k = 0; k < K; k += 4) {
        float a0 = a[k], a1 = a[k + 1], a2 = a[k + 2], a3 = a[k + 3];
        float2 w0 = *(const float2*)&W[(size_t)(k + 0) * PD + c0];
        float2 w1 = *(const float2*)&W[(size_t)(k + 1) * PD + c0];
        float2 w2 = *(const float2*)&W[(size_t)(k + 2) * PD + c0];
        float2 w3 = *(const float2*)&W[(size_t)(k + 3) * PD + c0];
        acc0 = fmaf(a0, w0.x, acc0); acc1 = fmaf(a0, w0.y, acc1);
        acc2 = fmaf(a1, w1.x, acc2); acc3 = fmaf(a1, w1.y, acc3);
        acc0 = fmaf(a2, w2.x, acc0); acc1 = fmaf(a2, w2.y, acc1);
        acc2 = fmaf(a3, w3.x, acc2); acc3 = fmaf(a3, w3.y, acc3);
    }
    float s = 1.f;
    if (cnts) s = 1.f / fmaxf((float)cnts[row], 1.f);
    float r0 = fmaf(acc0 + acc2, s, bias[c0]);
    float r1 = fmaf(acc1 + acc3, s, bias[c0 + 1]);
    if (relu) { r0 = fmaxf(r0, 0.f); r1 = fmaxf(r1, 0.f); }
    C[(size_t)row * ldc + c0] = r0;
    C[(size_t)row * ldc + c0 + 1] = r1;
}

// ---------------- dot: y[row] = A[row][:K] @ w + b ----------------
__global__ void k_dot(const float* __restrict__ A, const float* __restrict__ w,
                      const float* __restrict__ b, float* __restrict__ y, int K) {
    int row = blockIdx.x;
    int t = threadIdx.x;   // 64
    float s = 0.f;
    for (int k = t; k < K; k += 64) s = fmaf(A[(size_t)row * K + k], w[k], s);
    for (int off = 32; off; off >>= 1) s += __shfl_down(s, off);
    if (t == 0) y[row] = s + b[0];
}

// ---------------- logits + BCE loss ----------------
__global__ void k_final(const float* __restrict__ yi, const float* __restrict__ ys,
                        const float* __restrict__ ans, float* __restrict__ out) {
    __shared__ float red[128];
    int t = threadIdx.x;   // 128
    float l = fmaxf(yi[t], ys[t]);
    out[t] = l;
    float li = fmaxf(l, 0.f) + log1pf(expf(-fabsf(l))) - l * ans[t];
    red[t] = li;
    __syncthreads();
    for (int off = 64; off; off >>= 1) {
        if (t < off) red[t] += red[t + off];
        __syncthreads();
    }
    if (t == 0) out[BATCH] = red[0] / (float)BATCH;
}

extern "C" void kernel_launch(void* const* d_in, const int* in_sizes, int n_in,
                              void* d_out, int out_size, void* d_ws, size_t ws_size,
                              hipStream_t stream) {
    const float* image_features = (const float*)d_in[0];
    const float* text_features  = (const float*)d_in[1];
    const float* answer         = (const float*)d_in[2];
    const float* x_nodes        = (const float*)d_in[3];
    const int*   edge_index     = (const int*)d_in[4];
    const int*   batch_vec      = (const int*)d_in[5];
    const float* W_img = (const float*)d_in[6];
    const float* b_img = (const float*)d_in[7];
    const float* W_txt = (const float*)d_in[8];
    const float* b_txt = (const float*)d_in[9];
    const float* W1  = (const float*)d_in[10];
    const float* b1  = (const float*)d_in[11];
    const float* W2  = (const float*)d_in[12];
    const float* b2  = (const float*)d_in[13];
    const float* Wg  = (const float*)d_in[14];
    const float* bg  = (const float*)d_in[15];
    const float* Ws1 = (const float*)d_in[16];
    const float* bs1 = (const float*)d_in[17];
    const float* Ws2 = (const float*)d_in[18];
    const float* bs2 = (const float*)d_in[19];
    float* out = (float*)d_out;

    char* base = (char*)d_ws;
    size_t cur = 0;
    auto alloc = [&](size_t bytes) -> void* {
        void* r = base + cur;
        cur = (cur + bytes + 255) & ~(size_t)255;
        return r;
    };
    unsigned short* WgT = (unsigned short*)alloc((size_t)PD * PD * 2);
    unsigned short* hn  = (unsigned short*)alloc((size_t)N_NODES * PD * 2);
    int*   deg     = (int*)alloc((size_t)N_NODES * 4);
    float* dis     = (float*)alloc((size_t)N_NODES * 4);
    int*   row_ptr = (int*)alloc((size_t)(N_NODES + 1) * 4);
    int*   fill    = (int*)alloc((size_t)N_NODES * 4);
    int*   srcs    = (int*)alloc((size_t)N_EDGES * 4);
    float* sums    = (float*)alloc((size_t)BATCH * PD * 4);
    int*   cnts    = (int*)alloc((size_t)BATCH * 4);
    float* combined = (float*)alloc((size_t)BATCH * 1024 * 4);
    float* h1      = (float*)alloc((size_t)BATCH * PD * 4);
    float* hs      = (float*)alloc((size_t)BATCH * PD * 4);
    float* yi      = (float*)alloc((size_t)BATCH * 4);
    float* ys      = (float*)alloc((size_t)BATCH * 4);

    // symbolic-branch preprocessing
    hipLaunchKernelGGL(k_wgt, dim3(16, 16), dim3(32, 32), 0, stream, Wg, WgT, batch_vec, cnts);
    hipLaunchKernelGGL(k_init, dim3(256), dim3(256), 0, stream, deg, fill, sums);
    hipLaunchKernelGGL(k_deg, dim3(4096), dim3(256), 0, stream, edge_index, deg);
    hipLaunchKernelGGL(k_scan, dim3(1), dim3(1024), 0, stream, deg, row_ptr, dis);
    hipLaunchKernelGGL(k_scatter, dim3(4096), dim3(256), 0, stream, edge_index, row_ptr, fill, srcs);
    hipLaunchKernelGGL(k_gemm, dim3(N_NODES / 128, PD / 128), dim3(256), 0, stream,
                       x_nodes, WgT, dis, hn);
    hipLaunchKernelGGL(k_agg, dim3(N_NODES / NPB), dim3(256), 0, stream,
                       hn, dis, bg, row_ptr, srcs, batch_vec, sums);

    // implicit branch
    hipLaunchKernelGGL(k_lin, dim3(BATCH), dim3(256), 0, stream,
                       image_features, W_img, b_img, combined, CLIPD, 1024, 0, (const int*)nullptr);
    hipLaunchKernelGGL(k_lin, dim3(BATCH), dim3(256), 0, stream,
                       text_features, W_txt, b_txt, combined + PD, CLIPD, 1024, 0, (const int*)nullptr);
    hipLaunchKernelGGL(k_lin, dim3(BATCH), dim3(256), 0, stream,
                       combined, W1, b1, h1, 1024, PD, 1, (const int*)nullptr);
    hipLaunchKernelGGL(k_dot, dim3(BATCH), dim3(64), 0, stream, h1, W2, b2, yi, PD);

    // symbolic classifier (mean-pool folded in via cnts)
    hipLaunchKernelGGL(k_lin, dim3(BATCH), dim3(256), 0, stream,
                       sums, Ws1, bs1, hs, PD, PD, 1, cnts);
    hipLaunchKernelGGL(k_dot, dim3(BATCH), dim3(64), 0, stream, hs, Ws2, bs2, ys, PD);

    // fuse
    hipLaunchKernelGGL(k_final, dim3(1), dim3(128), 0, stream, yi, ys, answer, out);
}

// Round 5
// 544.074 us; speedup vs baseline: 2.4650x; 1.1429x over previous
//
#include <hip/hip_runtime.h>
#include <stdint.h>

#define N_NODES 65536
#define N_EDGES 1048576
#define BATCH   128
#define PD      512
#define CLIPD   768

typedef __attribute__((ext_vector_type(4))) float f32x4;
typedef __attribute__((ext_vector_type(2))) float f32x2;
typedef __attribute__((ext_vector_type(4))) int   i32x4;

__device__ __forceinline__ unsigned short f2b(float f) {
    uint32_t u = __float_as_uint(f);
    return (unsigned short)((u + 0x7fffu + ((u >> 16) & 1u)) >> 16);
}

// ---------------- Wg transpose+cast to bf16; batch counts via binary search on sorted bv ----------------
__global__ void k_wgt(const float* __restrict__ Wg, unsigned short* __restrict__ WgT,
                      const int* __restrict__ bv, int* __restrict__ cnts) {
    __shared__ float tile[32][33];
    int kb = blockIdx.x * 32, nb = blockIdx.y * 32;
    int tx = threadIdx.x, ty = threadIdx.y;
    if (kb == 0 && nb == 0) {
        int tid = ty * 32 + tx;
        if (tid < BATCH) {
            int lo = 0, hi = N_NODES;
            while (lo < hi) { int m = (lo + hi) >> 1; if (bv[m] < tid) lo = m + 1; else hi = m; }
            int lo2 = lo, hi2 = N_NODES;
            while (lo2 < hi2) { int m = (lo2 + hi2) >> 1; if (bv[m] < tid + 1) lo2 = m + 1; else hi2 = m; }
            cnts[tid] = lo2 - lo;
        }
    }
    tile[ty][tx] = Wg[(size_t)(kb + ty) * PD + nb + tx];
    __syncthreads();
    WgT[(size_t)(nb + ty) * PD + kb + tx] = f2b(tile[tx][ty]);
}

// ---------------- init: deg=1 (self loop), fill=0, sums=0 ----------------
__global__ void k_init(int* __restrict__ deg, int* __restrict__ fill,
                       float* __restrict__ sums) {
    int i = blockIdx.x * 256 + threadIdx.x;   // 65536 threads
    deg[i] = 1;
    fill[i] = 0;
    sums[i] = 0.f;                            // 128*512 == 65536
}

// ---------------- degree count over dst ----------------
__global__ void k_deg(const int* __restrict__ ei, int* __restrict__ deg) {
    int e = blockIdx.x * 256 + threadIdx.x;   // E threads
    atomicAdd(&deg[ei[N_EDGES + e]], 1);
}

// ---------------- coalesced wave-scan: row_ptr = exclusive scan of (deg-1); dis = rsqrt(deg) ----------------
__global__ void k_scan(const int* __restrict__ deg, int* __restrict__ row_ptr,
                       float* __restrict__ dis) {
    __shared__ int wsum[16];
    const int t = threadIdx.x;            // 1024
    const int w = t >> 6, l = t & 63;
    const int base = w * 4096;            // contiguous region per wave
    int s = 0;
    for (int i = 0; i < 64; ++i) s += deg[base + i * 64 + l];
    s -= 64;
#pragma unroll
    for (int off = 1; off < 64; off <<= 1) s += __shfl_xor(s, off);
    if (l == 0) wsum[w] = s;
    __syncthreads();
    int carry = 0;
    for (int i = 0; i < 16; ++i) carry += (i < w) ? wsum[i] : 0;
    int idx = base + l;
    int d = deg[idx];
    for (int i = 0; i < 64; ++i) {
        int dn = 0;
        if (i < 63) dn = deg[idx + 64];
        int v = d - 1;
        int inc = v;
#pragma unroll
        for (int off = 1; off < 64; off <<= 1) {
            int n = __shfl_up(inc, off);
            if (l >= off) inc += n;
        }
        row_ptr[idx] = carry + inc - v;
        dis[idx] = rsqrtf((float)d);
        carry += __shfl(inc, 63);
        idx += 64;
        d = dn;
    }
    if (t == 1023) row_ptr[N_NODES] = carry;  // == E
}

// ---------------- scatter edges into CSR buckets ----------------
__global__ void k_scatter(const int* __restrict__ ei, const int* __restrict__ row_ptr,
                          int* __restrict__ fill, int* __restrict__ srcs) {
    int e = blockIdx.x * 256 + threadIdx.x;
    int d = ei[N_EDGES + e];
    int pos = row_ptr[d] + atomicAdd(&fill[d], 1);
    srcs[pos] = ei[e];
}

// ---------------- big GEMM: hn8[i] = fp8_e4m3( dis[i] * (x[i] @ Wg) ) ----------------
// 128x128 tile, BK=32, 4 waves; reg-staged f32 A (cast in-kernel), bf16 B.
__device__ __forceinline__ void mfma16(f32x4& acc, i32x4 a, i32x4 b) {
    asm("v_mfma_f32_16x16x32_bf16 %0, %1, %2, %0" : "+v"(acc) : "v"(a), "v"(b));
}

__global__ __launch_bounds__(256) void k_gemm(const float* __restrict__ X,
                                              const unsigned short* __restrict__ WgT,
                                              const float* __restrict__ dis,
                                              uint8_t* __restrict__ hn8) {
    __shared__ __align__(16) unsigned short As[128 * 32];
    __shared__ __align__(16) unsigned short Bs[128 * 32];
    const int m0 = blockIdx.x * 128;
    const int n0 = blockIdx.y * 128;
    const int t = threadIdx.x;
    const int lane = t & 63, w = t >> 6;
    const int wr = w >> 1, wc = w & 1;
    const int g = lane >> 4, lr = lane & 15;

    f32x4 acc[4][4] = {};

    for (int k0 = 0; k0 < PD; k0 += 32) {
        __syncthreads();
#pragma unroll
        for (int it = 0; it < 4; ++it) {
            int idx = it * 256 + t;
            int r = idx >> 3, kc = (idx & 7) * 4;
            float4 v = *(const float4*)&X[(size_t)(m0 + r) * PD + k0 + kc];
            uint2 o;
            o.x = (uint32_t)f2b(v.x) | ((uint32_t)f2b(v.y) << 16);
            o.y = (uint32_t)f2b(v.z) | ((uint32_t)f2b(v.w) << 16);
            *(uint2*)&As[r * 32 + kc] = o;
        }
#pragma unroll
        for (int it = 0; it < 2; ++it) {
            int idx = it * 256 + t;
            int r = idx >> 2, kc = (idx & 3) * 8;
            *(uint4*)&Bs[r * 32 + kc] = *(const uint4*)&WgT[(size_t)(n0 + r) * PD + k0 + kc];
        }
        __syncthreads();

        i32x4 a[4], b[4];
#pragma unroll
        for (int i = 0; i < 4; ++i) a[i] = *(const i32x4*)&As[(wr * 64 + i * 16 + lr) * 32 + g * 8];
#pragma unroll
        for (int j = 0; j < 4; ++j) b[j] = *(const i32x4*)&Bs[(wc * 64 + j * 16 + lr) * 32 + g * 8];
#pragma unroll
        for (int i = 0; i < 4; ++i)
#pragma unroll
            for (int j = 0; j < 4; ++j) mfma16(acc[i][j], a[i], b[j]);
    }
    asm volatile("s_nop 7\n s_nop 7\n s_nop 7\n s_nop 7");

#pragma unroll
    for (int i = 0; i < 4; ++i) {
#pragma unroll
        for (int r = 0; r < 4; ++r) {
            int row = m0 + wr * 64 + i * 16 + g * 4 + r;
            float dd = dis[row];
#pragma unroll
            for (int j = 0; j < 4; ++j) {
                int col = n0 + wc * 64 + j * 16 + lr;
                float val = acc[i][j][r] * dd;
                uint32_t p = __builtin_amdgcn_cvt_pk_fp8_f32(val, val, 0, false);
                hn8[(size_t)row * PD + col] = (uint8_t)p;
            }
        }
    }
}

// ---------------- aggregation + bias + relu + fused mean-pool accumulation ----------------
// round-3 structure (measured best): 256 threads, 2 cols/thread, NPB=8; fp8 gather, 8-deep MLP.
#define NPB 8
__global__ __launch_bounds__(256) void k_agg(const uint8_t* __restrict__ hn8,
                                             const float* __restrict__ dis,
                                             const float* __restrict__ bg,
                                             const int* __restrict__ row_ptr,
                                             const int* __restrict__ srcs,
                                             const int* __restrict__ bv,
                                             float* __restrict__ sums) {
    const int t = threadIdx.x;
    const int c0 = t * 2;
    const int node0 = blockIdx.x * NPB;
    const float bg0 = bg[c0], bg1 = bg[c0 + 1];
    float s0 = 0.f, s1 = 0.f;
    int curb = bv[node0];
    for (int ni = 0; ni < NPB; ++ni) {
        int node = node0 + ni;
        int b = bv[node];
        if (b != curb) {
            atomicAdd(&sums[(size_t)curb * PD + c0], s0);
            atomicAdd(&sums[(size_t)curb * PD + c0 + 1], s1);
            s0 = s1 = 0.f;
            curb = b;
        }
        float a0 = 0.f, a1 = 0.f;
        int beg = row_ptr[node], end = row_ptr[node + 1];
        int e = beg;
        // 8-wide unroll: 8 independent fp8 gathers in flight per wait
        for (; e + 8 <= end; e += 8) {
            int sn0 = srcs[e + 0], sn1 = srcs[e + 1], sn2 = srcs[e + 2], sn3 = srcs[e + 3];
            int sn4 = srcs[e + 4], sn5 = srcs[e + 5], sn6 = srcs[e + 6], sn7 = srcs[e + 7];
            uint32_t v0 = *(const unsigned short*)&hn8[(size_t)sn0 * PD + c0];
            uint32_t v1 = *(const unsigned short*)&hn8[(size_t)sn1 * PD + c0];
            uint32_t v2 = *(const unsigned short*)&hn8[(size_t)sn2 * PD + c0];
            uint32_t v3 = *(const unsigned short*)&hn8[(size_t)sn3 * PD + c0];
            uint32_t v4 = *(const unsigned short*)&hn8[(size_t)sn4 * PD + c0];
            uint32_t v5 = *(const unsigned short*)&hn8[(size_t)sn5 * PD + c0];
            uint32_t v6 = *(const unsigned short*)&hn8[(size_t)sn6 * PD + c0];
            uint32_t v7 = *(const unsigned short*)&hn8[(size_t)sn7 * PD + c0];
            f32x2 f0 = __builtin_amdgcn_cvt_pk_f32_fp8(v0, false);
            f32x2 f1 = __builtin_amdgcn_cvt_pk_f32_fp8(v1, false);
            f32x2 f2 = __builtin_amdgcn_cvt_pk_f32_fp8(v2, false);
            f32x2 f3 = __builtin_amdgcn_cvt_pk_f32_fp8(v3, false);
            f32x2 f4 = __builtin_amdgcn_cvt_pk_f32_fp8(v4, false);
            f32x2 f5 = __builtin_amdgcn_cvt_pk_f32_fp8(v5, false);
            f32x2 f6 = __builtin_amdgcn_cvt_pk_f32_fp8(v6, false);
            f32x2 f7 = __builtin_amdgcn_cvt_pk_f32_fp8(v7, false);
            a0 += ((f0[0] + f1[0]) + (f2[0] + f3[0])) + ((f4[0] + f5[0]) + (f6[0] + f7[0]));
            a1 += ((f0[1] + f1[1]) + (f2[1] + f3[1])) + ((f4[1] + f5[1]) + (f6[1] + f7[1]));
        }
        for (; e < end; ++e) {
            int sn = srcs[e];
            uint32_t v = *(const unsigned short*)&hn8[(size_t)sn * PD + c0];
            f32x2 f = __builtin_amdgcn_cvt_pk_f32_fp8(v, false);
            a0 += f[0];
            a1 += f[1];
        }
        uint32_t v = *(const unsigned short*)&hn8[(size_t)node * PD + c0];  // self loop
        f32x2 f = __builtin_amdgcn_cvt_pk_f32_fp8(v, false);
        a0 += f[0];
        a1 += f[1];
        float dd = dis[node];
        a0 = fmaxf(fmaf(a0, dd, bg0), 0.f);
        a1 = fmaxf(fmaf(a1, dd, bg1), 0.f);
        s0 += a0;
        s1 += a1;
    }
    atomicAdd(&sums[(size_t)curb * PD + c0], s0);
    atomicAdd(&sums[(size_t)curb * PD + c0 + 1], s1);
}

// ---------------- small dense (Ncol==512): one block per row, 256 thr x 2 cols ----------------
__global__ __launch_bounds__(256) void k_lin(const float* __restrict__ A,
                                             const float* __restrict__ W,
                                             const float* __restrict__ bias,
                                             float* __restrict__ C,
                                             int K, int ldc, int relu,
                                             const int* __restrict__ cnts) {
    const int row = blockIdx.x;
    const int c0 = threadIdx.x * 2;
    const float* a = A + (size_t)row * K;
    float acc0 = 0.f, acc1 = 0.f, acc2 = 0.f, acc3 = 0.f;
    for (int k = 0; k < K; k += 4) {
        float a0 = a[k], a1 = a[k + 1], a2 = a[k + 2], a3 = a[k + 3];
        float2 w0 = *(const float2*)&W[(size_t)(k + 0) * PD + c0];
        float2 w1 = *(const float2*)&W[(size_t)(k + 1) * PD + c0];
        float2 w2 = *(const float2*)&W[(size_t)(k + 2) * PD + c0];
        float2 w3 = *(const float2*)&W[(size_t)(k + 3) * PD + c0];
        acc0 = fmaf(a0, w0.x, acc0); acc1 = fmaf(a0, w0.y, acc1);
        acc2 = fmaf(a1, w1.x, acc2); acc3 = fmaf(a1, w1.y, acc3);
        acc0 = fmaf(a2, w2.x, acc0); acc1 = fmaf(a2, w2.y, acc1);
        acc2 = fmaf(a3, w3.x, acc2); acc3 = fmaf(a3, w3.y, acc3);
    }
    float s = 1.f;
    if (cnts) s = 1.f / fmaxf((float)cnts[row], 1.f);
    float r0 = fmaf(acc0 + acc2, s, bias[c0]);
    float r1 = fmaf(acc1 + acc3, s, bias[c0 + 1]);
    if (relu) { r0 = fmaxf(r0, 0.f); r1 = fmaxf(r1, 0.f); }
    C[(size_t)row * ldc + c0] = r0;
    C[(size_t)row * ldc + c0 + 1] = r1;
}

// ---------------- dot: y[row] = A[row][:K] @ w + b ----------------
__global__ void k_dot(const float* __restrict__ A, const float* __restrict__ w,
                      const float* __restrict__ b, float* __restrict__ y, int K) {
    int row = blockIdx.x;
    int t = threadIdx.x;   // 64
    float s = 0.f;
    for (int k = t; k < K; k += 64) s = fmaf(A[(size_t)row * K + k], w[k], s);
    for (int off = 32; off; off >>= 1) s += __shfl_down(s, off);
    if (t == 0) y[row] = s + b[0];
}

// ---------------- logits + BCE loss ----------------
__global__ void k_final(const float* __restrict__ yi, const float* __restrict__ ys,
                        const float* __restrict__ ans, float* __restrict__ out) {
    __shared__ float red[128];
    int t = threadIdx.x;   // 128
    float l = fmaxf(yi[t], ys[t]);
    out[t] = l;
    float li = fmaxf(l, 0.f) + log1pf(expf(-fabsf(l))) - l * ans[t];
    red[t] = li;
    __syncthreads();
    for (int off = 64; off; off >>= 1) {
        if (t < off) red[t] += red[t + off];
        __syncthreads();
    }
    if (t == 0) out[BATCH] = red[0] / (float)BATCH;
}

extern "C" void kernel_launch(void* const* d_in, const int* in_sizes, int n_in,
                              void* d_out, int out_size, void* d_ws, size_t ws_size,
                              hipStream_t stream) {
    const float* image_features = (const float*)d_in[0];
    const float* text_features  = (const float*)d_in[1];
    const float* answer         = (const float*)d_in[2];
    const float* x_nodes        = (const float*)d_in[3];
    const int*   edge_index     = (const int*)d_in[4];
    const int*   batch_vec      = (const int*)d_in[5];
    const float* W_img = (const float*)d_in[6];
    const float* b_img = (const float*)d_in[7];
    const float* W_txt = (const float*)d_in[8];
    const float* b_txt = (const float*)d_in[9];
    const float* W1  = (const float*)d_in[10];
    const float* b1  = (const float*)d_in[11];
    const float* W2  = (const float*)d_in[12];
    const float* b2  = (const float*)d_in[13];
    const float* Wg  = (const float*)d_in[14];
    const float* bg  = (const float*)d_in[15];
    const float* Ws1 = (const float*)d_in[16];
    const float* bs1 = (const float*)d_in[17];
    const float* Ws2 = (const float*)d_in[18];
    const float* bs2 = (const float*)d_in[19];
    float* out = (float*)d_out;

    char* base = (char*)d_ws;
    size_t cur = 0;
    auto alloc = [&](size_t bytes) -> void* {
        void* r = base + cur;
        cur = (cur + bytes + 255) & ~(size_t)255;
        return r;
    };
    unsigned short* WgT = (unsigned short*)alloc((size_t)PD * PD * 2);
    uint8_t* hn8   = (uint8_t*)alloc((size_t)N_NODES * PD);
    int*   deg     = (int*)alloc((size_t)N_NODES * 4);
    float* dis     = (float*)alloc((size_t)N_NODES * 4);
    int*   row_ptr = (int*)alloc((size_t)(N_NODES + 1) * 4);
    int*   fill    = (int*)alloc((size_t)N_NODES * 4);
    int*   srcs    = (int*)alloc((size_t)N_EDGES * 4);
    float* sums    = (float*)alloc((size_t)BATCH * PD * 4);
    int*   cnts    = (int*)alloc((size_t)BATCH * 4);
    float* combined = (float*)alloc((size_t)BATCH * 1024 * 4);
    float* h1      = (float*)alloc((size_t)BATCH * PD * 4);
    float* hs      = (float*)alloc((size_t)BATCH * PD * 4);
    float* yi      = (float*)alloc((size_t)BATCH * 4);
    float* ys      = (float*)alloc((size_t)BATCH * 4);

    // symbolic-branch preprocessing
    hipLaunchKernelGGL(k_wgt, dim3(16, 16), dim3(32, 32), 0, stream, Wg, WgT, batch_vec, cnts);
    hipLaunchKernelGGL(k_init, dim3(256), dim3(256), 0, stream, deg, fill, sums);
    hipLaunchKernelGGL(k_deg, dim3(4096), dim3(256), 0, stream, edge_index, deg);
    hipLaunchKernelGGL(k_scan, dim3(1), dim3(1024), 0, stream, deg, row_ptr, dis);
    hipLaunchKernelGGL(k_scatter, dim3(4096), dim3(256), 0, stream, edge_index, row_ptr, fill, srcs);
    hipLaunchKernelGGL(k_gemm, dim3(N_NODES / 128, PD / 128), dim3(256), 0, stream,
                       x_nodes, WgT, dis, hn8);
    hipLaunchKernelGGL(k_agg, dim3(N_NODES / NPB), dim3(256), 0, stream,
                       hn8, dis, bg, row_ptr, srcs, batch_vec, sums);

    // implicit branch
    hipLaunchKernelGGL(k_lin, dim3(BATCH), dim3(256), 0, stream,
                       image_features, W_img, b_img, combined, CLIPD, 1024, 0, (const int*)nullptr);
    hipLaunchKernelGGL(k_lin, dim3(BATCH), dim3(256), 0, stream,
                       text_features, W_txt, b_txt, combined + PD, CLIPD, 1024, 0, (const int*)nullptr);
    hipLaunchKernelGGL(k_lin, dim3(BATCH), dim3(256), 0, stream,
                       combined, W1, b1, h1, 1024, PD, 1, (const int*)nullptr);
    hipLaunchKernelGGL(k_dot, dim3(BATCH), dim3(64), 0, stream, h1, W2, b2, yi, PD);

    // symbolic classifier (mean-pool folded in via cnts)
    hipLaunchKernelGGL(k_lin, dim3(BATCH), dim3(256), 0, stream,
                       sums, Ws1, bs1, hs, PD, PD, 1, cnts);
    hipLaunchKernelGGL(k_dot, dim3(BATCH), dim3(64), 0, stream, hs, Ws2, bs2, ys, PD);

    // fuse
    hipLaunchKernelGGL(k_final, dim3(1), dim3(128), 0, stream, yi, ys, answer, out);
}

// Round 6
// 417.709 us; speedup vs baseline: 3.2107x; 1.3025x over previous
//
#include <hip/hip_runtime.h>
#include <stdint.h>

#define N_NODES 65536
#define N_EDGES 1048576
#define BATCH   128
#define PD      512
#define CLIPD   768

typedef __attribute__((ext_vector_type(4))) float f32x4;
typedef __attribute__((ext_vector_type(2))) float f32x2;
typedef __attribute__((ext_vector_type(4))) int   i32x4;

__device__ __forceinline__ unsigned short f2b(float f) {
    uint32_t u = __float_as_uint(f);
    return (unsigned short)((u + 0x7fffu + ((u >> 16) & 1u)) >> 16);
}

// ---------------- Wg transpose+cast to bf16; batch counts via binary search on sorted bv ----------------
__global__ void k_wgt(const float* __restrict__ Wg, unsigned short* __restrict__ WgT,
                      const int* __restrict__ bv, int* __restrict__ cnts) {
    __shared__ float tile[32][33];
    int kb = blockIdx.x * 32, nb = blockIdx.y * 32;
    int tx = threadIdx.x, ty = threadIdx.y;
    if (kb == 0 && nb == 0) {
        int tid = ty * 32 + tx;
        if (tid < BATCH) {
            int lo = 0, hi = N_NODES;
            while (lo < hi) { int m = (lo + hi) >> 1; if (bv[m] < tid) lo = m + 1; else hi = m; }
            int lo2 = lo, hi2 = N_NODES;
            while (lo2 < hi2) { int m = (lo2 + hi2) >> 1; if (bv[m] < tid + 1) lo2 = m + 1; else hi2 = m; }
            cnts[tid] = lo2 - lo;
        }
    }
    tile[ty][tx] = Wg[(size_t)(kb + ty) * PD + nb + tx];
    __syncthreads();
    WgT[(size_t)(nb + ty) * PD + kb + tx] = f2b(tile[tx][ty]);
}

// ---------------- init: deg=1 (self loop), fill=0, sums=0 ----------------
__global__ void k_init(int* __restrict__ deg, int* __restrict__ fill,
                       float* __restrict__ sums) {
    int i = blockIdx.x * 256 + threadIdx.x;   // 65536 threads
    deg[i] = 1;
    fill[i] = 0;
    sums[i] = 0.f;                            // 128*512 == 65536
}

// ---------------- degree count over dst ----------------
__global__ void k_deg(const int* __restrict__ ei, int* __restrict__ deg) {
    int e = blockIdx.x * 256 + threadIdx.x;   // E threads
    atomicAdd(&deg[ei[N_EDGES + e]], 1);
}

// ---------------- coalesced wave-scan: row_ptr = exclusive scan of (deg-1); dis = rsqrt(deg) ----------------
__global__ void k_scan(const int* __restrict__ deg, int* __restrict__ row_ptr,
                       float* __restrict__ dis) {
    __shared__ int wsum[16];
    const int t = threadIdx.x;            // 1024
    const int w = t >> 6, l = t & 63;
    const int base = w * 4096;            // contiguous region per wave
    int s = 0;
    for (int i = 0; i < 64; ++i) s += deg[base + i * 64 + l];
    s -= 64;
#pragma unroll
    for (int off = 1; off < 64; off <<= 1) s += __shfl_xor(s, off);
    if (l == 0) wsum[w] = s;
    __syncthreads();
    int carry = 0;
    for (int i = 0; i < 16; ++i) carry += (i < w) ? wsum[i] : 0;
    int idx = base + l;
    int d = deg[idx];
    for (int i = 0; i < 64; ++i) {
        int dn = 0;
        if (i < 63) dn = deg[idx + 64];
        int v = d - 1;
        int inc = v;
#pragma unroll
        for (int off = 1; off < 64; off <<= 1) {
            int n = __shfl_up(inc, off);
            if (l >= off) inc += n;
        }
        row_ptr[idx] = carry + inc - v;
        dis[idx] = rsqrtf((float)d);
        carry += __shfl(inc, 63);
        idx += 64;
        d = dn;
    }
    if (t == 1023) row_ptr[N_NODES] = carry;  // == E
}

// ---------------- scatter edges into CSR buckets ----------------
__global__ void k_scatter(const int* __restrict__ ei, const int* __restrict__ row_ptr,
                          int* __restrict__ fill, int* __restrict__ srcs) {
    int e = blockIdx.x * 256 + threadIdx.x;
    int d = ei[N_EDGES + e];
    int pos = row_ptr[d] + atomicAdd(&fill[d], 1);
    srcs[pos] = ei[e];
}

// ---------------- big GEMM: hn8[i] = fp8_e4m3( dis[i] * (x[i] @ Wg) ) ----------------
__device__ __forceinline__ void mfma16(f32x4& acc, i32x4 a, i32x4 b) {
    asm("v_mfma_f32_16x16x32_bf16 %0, %1, %2, %0" : "+v"(acc) : "v"(a), "v"(b));
}

__global__ __launch_bounds__(256) void k_gemm(const float* __restrict__ X,
                                              const unsigned short* __restrict__ WgT,
                                              const float* __restrict__ dis,
                                              uint8_t* __restrict__ hn8) {
    __shared__ __align__(16) unsigned short As[128 * 32];
    __shared__ __align__(16) unsigned short Bs[128 * 32];
    const int m0 = blockIdx.x * 128;
    const int n0 = blockIdx.y * 128;
    const int t = threadIdx.x;
    const int lane = t & 63, w = t >> 6;
    const int wr = w >> 1, wc = w & 1;
    const int g = lane >> 4, lr = lane & 15;

    f32x4 acc[4][4] = {};

    for (int k0 = 0; k0 < PD; k0 += 32) {
        __syncthreads();
#pragma unroll
        for (int it = 0; it < 4; ++it) {
            int idx = it * 256 + t;
            int r = idx >> 3, kc = (idx & 7) * 4;
            float4 v = *(const float4*)&X[(size_t)(m0 + r) * PD + k0 + kc];
            uint2 o;
            o.x = (uint32_t)f2b(v.x) | ((uint32_t)f2b(v.y) << 16);
            o.y = (uint32_t)f2b(v.z) | ((uint32_t)f2b(v.w) << 16);
            *(uint2*)&As[r * 32 + kc] = o;
        }
#pragma unroll
        for (int it = 0; it < 2; ++it) {
            int idx = it * 256 + t;
            int r = idx >> 2, kc = (idx & 3) * 8;
            *(uint4*)&Bs[r * 32 + kc] = *(const uint4*)&WgT[(size_t)(n0 + r) * PD + k0 + kc];
        }
        __syncthreads();

        i32x4 a[4], b[4];
#pragma unroll
        for (int i = 0; i < 4; ++i) a[i] = *(const i32x4*)&As[(wr * 64 + i * 16 + lr) * 32 + g * 8];
#pragma unroll
        for (int j = 0; j < 4; ++j) b[j] = *(const i32x4*)&Bs[(wc * 64 + j * 16 + lr) * 32 + g * 8];
#pragma unroll
        for (int i = 0; i < 4; ++i)
#pragma unroll
            for (int j = 0; j < 4; ++j) mfma16(acc[i][j], a[i], b[j]);
    }
    asm volatile("s_nop 7\n s_nop 7\n s_nop 7\n s_nop 7");

#pragma unroll
    for (int i = 0; i < 4; ++i) {
#pragma unroll
        for (int r = 0; r < 4; ++r) {
            int row = m0 + wr * 64 + i * 16 + g * 4 + r;
            float dd = dis[row];
#pragma unroll
            for (int j = 0; j < 4; ++j) {
                int col = n0 + wc * 64 + j * 16 + lr;
                float val = acc[i][j][r] * dd;
                uint32_t p = __builtin_amdgcn_cvt_pk_fp8_f32(val, val, 0, false);
                hn8[(size_t)row * PD + col] = (uint8_t)p;
            }
        }
    }
}

// ---------------- aggregation + bias + relu + fused mean-pool accumulation ----------------
#define NPB 8
__global__ __launch_bounds__(256) void k_agg(const uint8_t* __restrict__ hn8,
                                             const float* __restrict__ dis,
                                             const float* __restrict__ bg,
                                             const int* __restrict__ row_ptr,
                                             const int* __restrict__ srcs,
                                             const int* __restrict__ bv,
                                             float* __restrict__ sums) {
    const int t = threadIdx.x;
    const int c0 = t * 2;
    const int node0 = blockIdx.x * NPB;
    const float bg0 = bg[c0], bg1 = bg[c0 + 1];
    float s0 = 0.f, s1 = 0.f;
    int curb = bv[node0];
    for (int ni = 0; ni < NPB; ++ni) {
        int node = node0 + ni;
        int b = bv[node];
        if (b != curb) {
            atomicAdd(&sums[(size_t)curb * PD + c0], s0);
            atomicAdd(&sums[(size_t)curb * PD + c0 + 1], s1);
            s0 = s1 = 0.f;
            curb = b;
        }
        float a0 = 0.f, a1 = 0.f;
        int beg = row_ptr[node], end = row_ptr[node + 1];
        int e = beg;
        for (; e + 8 <= end; e += 8) {
            int sn0 = srcs[e + 0], sn1 = srcs[e + 1], sn2 = srcs[e + 2], sn3 = srcs[e + 3];
            int sn4 = srcs[e + 4], sn5 = srcs[e + 5], sn6 = srcs[e + 6], sn7 = srcs[e + 7];
            uint32_t v0 = *(const unsigned short*)&hn8[(size_t)sn0 * PD + c0];
            uint32_t v1 = *(const unsigned short*)&hn8[(size_t)sn1 * PD + c0];
            uint32_t v2 = *(const unsigned short*)&hn8[(size_t)sn2 * PD + c0];
            uint32_t v3 = *(const unsigned short*)&hn8[(size_t)sn3 * PD + c0];
            uint32_t v4 = *(const unsigned short*)&hn8[(size_t)sn4 * PD + c0];
            uint32_t v5 = *(const unsigned short*)&hn8[(size_t)sn5 * PD + c0];
            uint32_t v6 = *(const unsigned short*)&hn8[(size_t)sn6 * PD + c0];
            uint32_t v7 = *(const unsigned short*)&hn8[(size_t)sn7 * PD + c0];
            f32x2 f0 = __builtin_amdgcn_cvt_pk_f32_fp8(v0, false);
            f32x2 f1 = __builtin_amdgcn_cvt_pk_f32_fp8(v1, false);
            f32x2 f2 = __builtin_amdgcn_cvt_pk_f32_fp8(v2, false);
            f32x2 f3 = __builtin_amdgcn_cvt_pk_f32_fp8(v3, false);
            f32x2 f4 = __builtin_amdgcn_cvt_pk_f32_fp8(v4, false);
            f32x2 f5 = __builtin_amdgcn_cvt_pk_f32_fp8(v5, false);
            f32x2 f6 = __builtin_amdgcn_cvt_pk_f32_fp8(v6, false);
            f32x2 f7 = __builtin_amdgcn_cvt_pk_f32_fp8(v7, false);
            a0 += ((f0[0] + f1[0]) + (f2[0] + f3[0])) + ((f4[0] + f5[0]) + (f6[0] + f7[0]));
            a1 += ((f0[1] + f1[1]) + (f2[1] + f3[1])) + ((f4[1] + f5[1]) + (f6[1] + f7[1]));
        }
        for (; e < end; ++e) {
            int sn = srcs[e];
            uint32_t v = *(const unsigned short*)&hn8[(size_t)sn * PD + c0];
            f32x2 f = __builtin_amdgcn_cvt_pk_f32_fp8(v, false);
            a0 += f[0];
            a1 += f[1];
        }
        uint32_t v = *(const unsigned short*)&hn8[(size_t)node * PD + c0];  // self loop
        f32x2 f = __builtin_amdgcn_cvt_pk_f32_fp8(v, false);
        a0 += f[0];
        a1 += f[1];
        float dd = dis[node];
        a0 = fmaxf(fmaf(a0, dd, bg0), 0.f);
        a1 = fmaxf(fmaf(a1, dd, bg1), 0.f);
        s0 += a0;
        s1 += a1;
    }
    atomicAdd(&sums[(size_t)curb * PD + c0], s0);
    atomicAdd(&sums[(size_t)curb * PD + c0 + 1], s1);
}

// ---------------- dense partial: P[row][kc][c] = A[row][kc*256:(kc+1)*256] @ W[.., c] ----------------
// grid (BATCH, nch); 256 threads x 2 cols; 8-deep independent load pipeline.
__global__ __launch_bounds__(256) void k_lin_part(const float* __restrict__ A,
                                                  const float* __restrict__ W,
                                                  float* __restrict__ P,
                                                  int K) {
    const int row = blockIdx.x;
    const int kc = blockIdx.y;
    const int c0 = threadIdx.x * 2;
    const float* a = A + (size_t)row * K + kc * 256;
    const float* wp = W + (size_t)kc * 256 * PD + c0;
    float acc0 = 0.f, acc1 = 0.f, acc2 = 0.f, acc3 = 0.f;
    float acc4 = 0.f, acc5 = 0.f, acc6 = 0.f, acc7 = 0.f;
#pragma unroll 4
    for (int k = 0; k < 256; k += 8) {
        float a0 = a[k + 0], a1 = a[k + 1], a2 = a[k + 2], a3 = a[k + 3];
        float a4 = a[k + 4], a5 = a[k + 5], a6 = a[k + 6], a7 = a[k + 7];
        float2 w0 = *(const float2*)&wp[(size_t)(k + 0) * PD];
        float2 w1 = *(const float2*)&wp[(size_t)(k + 1) * PD];
        float2 w2 = *(const float2*)&wp[(size_t)(k + 2) * PD];
        float2 w3 = *(const float2*)&wp[(size_t)(k + 3) * PD];
        float2 w4 = *(const float2*)&wp[(size_t)(k + 4) * PD];
        float2 w5 = *(const float2*)&wp[(size_t)(k + 5) * PD];
        float2 w6 = *(const float2*)&wp[(size_t)(k + 6) * PD];
        float2 w7 = *(const float2*)&wp[(size_t)(k + 7) * PD];
        acc0 = fmaf(a0, w0.x, acc0); acc1 = fmaf(a0, w0.y, acc1);
        acc2 = fmaf(a1, w1.x, acc2); acc3 = fmaf(a1, w1.y, acc3);
        acc4 = fmaf(a2, w2.x, acc4); acc5 = fmaf(a2, w2.y, acc5);
        acc6 = fmaf(a3, w3.x, acc6); acc7 = fmaf(a3, w3.y, acc7);
        acc0 = fmaf(a4, w4.x, acc0); acc1 = fmaf(a4, w4.y, acc1);
        acc2 = fmaf(a5, w5.x, acc2); acc3 = fmaf(a5, w5.y, acc3);
        acc4 = fmaf(a6, w6.x, acc4); acc5 = fmaf(a6, w6.y, acc5);
        acc6 = fmaf(a7, w7.x, acc6); acc7 = fmaf(a7, w7.y, acc7);
    }
    float r0 = (acc0 + acc2) + (acc4 + acc6);
    float r1 = (acc1 + acc3) + (acc5 + acc7);
    P[((size_t)row * 4 + kc) * PD + c0] = r0;
    P[((size_t)row * 4 + kc) * PD + c0 + 1] = r1;
}

// ---------------- reduce partials + (mean-scale) + bias + relu ----------------
__global__ __launch_bounds__(256) void k_lin_red(const float* __restrict__ P,
                                                 const float* __restrict__ bias,
                                                 float* __restrict__ C,
                                                 int nch, int ldc, int relu,
                                                 const int* __restrict__ cnts) {
    const int row = blockIdx.x;
    const int c0 = threadIdx.x * 2;
    const float* p = P + (size_t)row * 4 * PD + c0;
    float r0 = p[0], r1 = p[1];
    if (nch > 1) { r0 += p[PD];     r1 += p[PD + 1]; }
    if (nch > 2) { r0 += p[2 * PD]; r1 += p[2 * PD + 1]; }
    if (nch > 3) { r0 += p[3 * PD]; r1 += p[3 * PD + 1]; }
    float s = 1.f;
    if (cnts) s = 1.f / fmaxf((float)cnts[row], 1.f);
    r0 = fmaf(r0, s, bias[c0]);
    r1 = fmaf(r1, s, bias[c0 + 1]);
    if (relu) { r0 = fmaxf(r0, 0.f); r1 = fmaxf(r1, 0.f); }
    C[(size_t)row * ldc + c0] = r0;
    C[(size_t)row * ldc + c0 + 1] = r1;
}

// ---------------- dot: y[row] = A[row][:K] @ w + b ----------------
__global__ void k_dot(const float* __restrict__ A, const float* __restrict__ w,
                      const float* __restrict__ b, float* __restrict__ y, int K) {
    int row = blockIdx.x;
    int t = threadIdx.x;   // 64
    float s = 0.f;
    for (int k = t; k < K; k += 64) s = fmaf(A[(size_t)row * K + k], w[k], s);
    for (int off = 32; off; off >>= 1) s += __shfl_down(s, off);
    if (t == 0) y[row] = s + b[0];
}

// ---------------- logits + BCE loss ----------------
__global__ void k_final(const float* __restrict__ yi, const float* __restrict__ ys,
                        const float* __restrict__ ans, float* __restrict__ out) {
    __shared__ float red[128];
    int t = threadIdx.x;   // 128
    float l = fmaxf(yi[t], ys[t]);
    out[t] = l;
    float li = fmaxf(l, 0.f) + log1pf(expf(-fabsf(l))) - l * ans[t];
    red[t] = li;
    __syncthreads();
    for (int off = 64; off; off >>= 1) {
        if (t < off) red[t] += red[t + off];
        __syncthreads();
    }
    if (t == 0) out[BATCH] = red[0] / (float)BATCH;
}

extern "C" void kernel_launch(void* const* d_in, const int* in_sizes, int n_in,
                              void* d_out, int out_size, void* d_ws, size_t ws_size,
                              hipStream_t stream) {
    const float* image_features = (const float*)d_in[0];
    const float* text_features  = (const float*)d_in[1];
    const float* answer         = (const float*)d_in[2];
    const float* x_nodes        = (const float*)d_in[3];
    const int*   edge_index     = (const int*)d_in[4];
    const int*   batch_vec      = (const int*)d_in[5];
    const float* W_img = (const float*)d_in[6];
    const float* b_img = (const float*)d_in[7];
    const float* W_txt = (const float*)d_in[8];
    const float* b_txt = (const float*)d_in[9];
    const float* W1  = (const float*)d_in[10];
    const float* b1  = (const float*)d_in[11];
    const float* W2  = (const float*)d_in[12];
    const float* b2  = (const float*)d_in[13];
    const float* Wg  = (const float*)d_in[14];
    const float* bg  = (const float*)d_in[15];
    const float* Ws1 = (const float*)d_in[16];
    const float* bs1 = (const float*)d_in[17];
    const float* Ws2 = (const float*)d_in[18];
    const float* bs2 = (const float*)d_in[19];
    float* out = (float*)d_out;

    char* base = (char*)d_ws;
    size_t cur = 0;
    auto alloc = [&](size_t bytes) -> void* {
        void* r = base + cur;
        cur = (cur + bytes + 255) & ~(size_t)255;
        return r;
    };
    unsigned short* WgT = (unsigned short*)alloc((size_t)PD * PD * 2);
    uint8_t* hn8   = (uint8_t*)alloc((size_t)N_NODES * PD);
    int*   deg     = (int*)alloc((size_t)N_NODES * 4);
    float* dis     = (float*)alloc((size_t)N_NODES * 4);
    int*   row_ptr = (int*)alloc((size_t)(N_NODES + 1) * 4);
    int*   fill    = (int*)alloc((size_t)N_NODES * 4);
    int*   srcs    = (int*)alloc((size_t)N_EDGES * 4);
    float* sums    = (float*)alloc((size_t)BATCH * PD * 4);
    int*   cnts    = (int*)alloc((size_t)BATCH * 4);
    float* Ppart   = (float*)alloc((size_t)BATCH * 4 * PD * 4);
    float* combined = (float*)alloc((size_t)BATCH * 1024 * 4);
    float* h1      = (float*)alloc((size_t)BATCH * PD * 4);
    float* hs      = (float*)alloc((size_t)BATCH * PD * 4);
    float* yi      = (float*)alloc((size_t)BATCH * 4);
    float* ys      = (float*)alloc((size_t)BATCH * 4);

    // symbolic-branch preprocessing
    hipLaunchKernelGGL(k_wgt, dim3(16, 16), dim3(32, 32), 0, stream, Wg, WgT, batch_vec, cnts);
    hipLaunchKernelGGL(k_init, dim3(256), dim3(256), 0, stream, deg, fill, sums);
    hipLaunchKernelGGL(k_deg, dim3(4096), dim3(256), 0, stream, edge_index, deg);
    hipLaunchKernelGGL(k_scan, dim3(1), dim3(1024), 0, stream, deg, row_ptr, dis);
    hipLaunchKernelGGL(k_scatter, dim3(4096), dim3(256), 0, stream, edge_index, row_ptr, fill, srcs);
    hipLaunchKernelGGL(k_gemm, dim3(N_NODES / 128, PD / 128), dim3(256), 0, stream,
                       x_nodes, WgT, dis, hn8);
    hipLaunchKernelGGL(k_agg, dim3(N_NODES / NPB), dim3(256), 0, stream,
                       hn8, dis, bg, row_ptr, srcs, batch_vec, sums);

    // implicit branch: img proj -> combined[:,0:512]
    hipLaunchKernelGGL(k_lin_part, dim3(BATCH, 3), dim3(256), 0, stream,
                       image_features, W_img, Ppart, CLIPD);
    hipLaunchKernelGGL(k_lin_red, dim3(BATCH), dim3(256), 0, stream,
                       Ppart, b_img, combined, 3, 1024, 0, (const int*)nullptr);
    // txt proj -> combined[:,512:1024]
    hipLaunchKernelGGL(k_lin_part, dim3(BATCH, 3), dim3(256), 0, stream,
                       text_features, W_txt, Ppart, CLIPD);
    hipLaunchKernelGGL(k_lin_red, dim3(BATCH), dim3(256), 0, stream,
                       Ppart, b_txt, combined + PD, 3, 1024, 0, (const int*)nullptr);
    // classifier layer 1 (K=1024)
    hipLaunchKernelGGL(k_lin_part, dim3(BATCH, 4), dim3(256), 0, stream,
                       combined, W1, Ppart, 1024);
    hipLaunchKernelGGL(k_lin_red, dim3(BATCH), dim3(256), 0, stream,
                       Ppart, b1, h1, 4, PD, 1, (const int*)nullptr);
    hipLaunchKernelGGL(k_dot, dim3(BATCH), dim3(64), 0, stream, h1, W2, b2, yi, PD);

    // symbolic classifier (mean-pool folded via cnts), K=512
    hipLaunchKernelGGL(k_lin_part, dim3(BATCH, 2), dim3(256), 0, stream,
                       sums, Ws1, Ppart, PD);
    hipLaunchKernelGGL(k_lin_red, dim3(BATCH), dim3(256), 0, stream,
                       Ppart, bs1, hs, 2, PD, 1, cnts);
    hipLaunchKernelGGL(k_dot, dim3(BATCH), dim3(64), 0, stream, hs, Ws2, bs2, ys, PD);

    // fuse
    hipLaunchKernelGGL(k_final, dim3(1), dim3(128), 0, stream, yi, ys, answer, out);
}

// Round 7
// 395.750 us; speedup vs baseline: 3.3888x; 1.0555x over previous
//
#include <hip/hip_runtime.h>
#include <stdint.h>

#define N_NODES 65536
#define N_EDGES 1048576
#define BATCH   128
#define PD      512
#define CLIPD   768

typedef __attribute__((ext_vector_type(4))) float f32x4;
typedef __attribute__((ext_vector_type(2))) float f32x2;
typedef __attribute__((ext_vector_type(4))) int   i32x4;

__device__ __forceinline__ unsigned short f2b(float f) {
    uint32_t u = __float_as_uint(f);
    return (unsigned short)((u + 0x7fffu + ((u >> 16) & 1u)) >> 16);
}

// ---------------- Wg transpose+cast to bf16; batch counts via binary search on sorted bv ----------------
__global__ void k_wgt(const float* __restrict__ Wg, unsigned short* __restrict__ WgT,
                      const int* __restrict__ bv, int* __restrict__ cnts) {
    __shared__ float tile[32][33];
    int kb = blockIdx.x * 32, nb = blockIdx.y * 32;
    int tx = threadIdx.x, ty = threadIdx.y;
    if (kb == 0 && nb == 0) {
        int tid = ty * 32 + tx;
        if (tid < BATCH) {
            int lo = 0, hi = N_NODES;
            while (lo < hi) { int m = (lo + hi) >> 1; if (bv[m] < tid) lo = m + 1; else hi = m; }
            int lo2 = lo, hi2 = N_NODES;
            while (lo2 < hi2) { int m = (lo2 + hi2) >> 1; if (bv[m] < tid + 1) lo2 = m + 1; else hi2 = m; }
            cnts[tid] = lo2 - lo;
        }
    }
    tile[ty][tx] = Wg[(size_t)(kb + ty) * PD + nb + tx];
    __syncthreads();
    WgT[(size_t)(nb + ty) * PD + kb + tx] = f2b(tile[tx][ty]);
}

// ---------------- init: deg=1 (self loop), fill=0, sums=0 ----------------
__global__ void k_init(int* __restrict__ deg, int* __restrict__ fill,
                       float* __restrict__ sums) {
    int i = blockIdx.x * 256 + threadIdx.x;   // 65536 threads
    deg[i] = 1;
    fill[i] = 0;
    sums[i] = 0.f;                            // 128*512 == 65536
}

// ---------------- degree count over dst ----------------
__global__ void k_deg(const int* __restrict__ ei, int* __restrict__ deg) {
    int e = blockIdx.x * 256 + threadIdx.x;   // E threads
    atomicAdd(&deg[ei[N_EDGES + e]], 1);
}

// ---------------- coalesced wave-scan: row_ptr = exclusive scan of (deg-1); dis = rsqrt(deg) ----------------
__global__ void k_scan(const int* __restrict__ deg, int* __restrict__ row_ptr,
                       float* __restrict__ dis) {
    __shared__ int wsum[16];
    const int t = threadIdx.x;            // 1024
    const int w = t >> 6, l = t & 63;
    const int base = w * 4096;            // contiguous region per wave
    int s = 0;
    for (int i = 0; i < 64; ++i) s += deg[base + i * 64 + l];
    s -= 64;
#pragma unroll
    for (int off = 1; off < 64; off <<= 1) s += __shfl_xor(s, off);
    if (l == 0) wsum[w] = s;
    __syncthreads();
    int carry = 0;
    for (int i = 0; i < 16; ++i) carry += (i < w) ? wsum[i] : 0;
    int idx = base + l;
    int d = deg[idx];
    for (int i = 0; i < 64; ++i) {
        int dn = 0;
        if (i < 63) dn = deg[idx + 64];
        int v = d - 1;
        int inc = v;
#pragma unroll
        for (int off = 1; off < 64; off <<= 1) {
            int n = __shfl_up(inc, off);
            if (l >= off) inc += n;
        }
        row_ptr[idx] = carry + inc - v;
        dis[idx] = rsqrtf((float)d);
        carry += __shfl(inc, 63);
        idx += 64;
        d = dn;
    }
    if (t == 1023) row_ptr[N_NODES] = carry;  // == E
}

// ---------------- scatter edges into CSR buckets ----------------
__global__ void k_scatter(const int* __restrict__ ei, const int* __restrict__ row_ptr,
                          int* __restrict__ fill, int* __restrict__ srcs) {
    int e = blockIdx.x * 256 + threadIdx.x;
    int d = ei[N_EDGES + e];
    int pos = row_ptr[d] + atomicAdd(&fill[d], 1);
    srcs[pos] = ei[e];
}

// ---------------- big GEMM: hn8[i] = fp8_e4m3( dis[i] * (x[i] @ Wg) ) ----------------
// 128x256 tile (BN=256 halves X re-reads + staging VALU per FLOP), BK=32, 4 waves.
__device__ __forceinline__ void mfma16(f32x4& acc, i32x4 a, i32x4 b) {
    asm("v_mfma_f32_16x16x32_bf16 %0, %1, %2, %0" : "+v"(acc) : "v"(a), "v"(b));
}

__global__ __launch_bounds__(256) void k_gemm(const float* __restrict__ X,
                                              const unsigned short* __restrict__ WgT,
                                              const float* __restrict__ dis,
                                              uint8_t* __restrict__ hn8) {
    __shared__ __align__(16) unsigned short As[128 * 32];
    __shared__ __align__(16) unsigned short Bs[256 * 32];
    const int m0 = blockIdx.x * 128;
    const int n0 = blockIdx.y * 256;
    const int t = threadIdx.x;
    const int lane = t & 63, w = t >> 6;
    const int wr = w >> 1, wc = w & 1;       // wave tile: 64 rows x 128 cols
    const int g = lane >> 4, lr = lane & 15;

    f32x4 acc[4][8] = {};

    for (int k0 = 0; k0 < PD; k0 += 32) {
        __syncthreads();
        // stage A: 128x32 f32 -> bf16
#pragma unroll
        for (int it = 0; it < 4; ++it) {
            int idx = it * 256 + t;
            int r = idx >> 3, kc = (idx & 7) * 4;
            float4 v = *(const float4*)&X[(size_t)(m0 + r) * PD + k0 + kc];
            uint2 o;
            o.x = (uint32_t)f2b(v.x) | ((uint32_t)f2b(v.y) << 16);
            o.y = (uint32_t)f2b(v.z) | ((uint32_t)f2b(v.w) << 16);
            *(uint2*)&As[r * 32 + kc] = o;
        }
        // stage B: 256x32 bf16
#pragma unroll
        for (int it = 0; it < 4; ++it) {
            int idx = it * 256 + t;
            int r = idx >> 2, kc = (idx & 3) * 8;
            *(uint4*)&Bs[r * 32 + kc] = *(const uint4*)&WgT[(size_t)(n0 + r) * PD + k0 + kc];
        }
        __syncthreads();

        i32x4 a[4], b[8];
#pragma unroll
        for (int i = 0; i < 4; ++i) a[i] = *(const i32x4*)&As[(wr * 64 + i * 16 + lr) * 32 + g * 8];
#pragma unroll
        for (int j = 0; j < 8; ++j) b[j] = *(const i32x4*)&Bs[(wc * 128 + j * 16 + lr) * 32 + g * 8];
#pragma unroll
        for (int i = 0; i < 4; ++i)
#pragma unroll
            for (int j = 0; j < 8; ++j) mfma16(acc[i][j], a[i], b[j]);
    }
    asm volatile("s_nop 7\n s_nop 7\n s_nop 7\n s_nop 7");

#pragma unroll
    for (int i = 0; i < 4; ++i) {
#pragma unroll
        for (int r = 0; r < 4; ++r) {
            int row = m0 + wr * 64 + i * 16 + g * 4 + r;
            float dd = dis[row];
#pragma unroll
            for (int j = 0; j < 8; ++j) {
                int col = n0 + wc * 128 + j * 16 + lr;
                float val = acc[i][j][r] * dd;
                uint32_t p = __builtin_amdgcn_cvt_pk_fp8_f32(val, val, 0, false);
                hn8[(size_t)row * PD + col] = (uint8_t)p;
            }
        }
    }
}

// ---------------- aggregation + bias + relu + fused mean-pool accumulation ----------------
// 256 threads, 2 cols/thread, NPB=8; fp8 gather, 16-deep load pipeline.
#define NPB 8
__global__ __launch_bounds__(256) void k_agg(const uint8_t* __restrict__ hn8,
                                             const float* __restrict__ dis,
                                             const float* __restrict__ bg,
                                             const int* __restrict__ row_ptr,
                                             const int* __restrict__ srcs,
                                             const int* __restrict__ bv,
                                             float* __restrict__ sums) {
    const int t = threadIdx.x;
    const int c0 = t * 2;
    const int node0 = blockIdx.x * NPB;
    const float bg0 = bg[c0], bg1 = bg[c0 + 1];
    float s0 = 0.f, s1 = 0.f;
    int curb = bv[node0];
    for (int ni = 0; ni < NPB; ++ni) {
        int node = node0 + ni;
        int b = bv[node];
        if (b != curb) {
            atomicAdd(&sums[(size_t)curb * PD + c0], s0);
            atomicAdd(&sums[(size_t)curb * PD + c0 + 1], s1);
            s0 = s1 = 0.f;
            curb = b;
        }
        float a0 = 0.f, a1 = 0.f;
        int beg = row_ptr[node], end = row_ptr[node + 1];
        int e = beg;
        // 16-deep: issue all loads before any use
        for (; e + 16 <= end; e += 16) {
            int sn[16];
#pragma unroll
            for (int q = 0; q < 16; ++q) sn[q] = srcs[e + q];
            uint32_t v[16];
#pragma unroll
            for (int q = 0; q < 16; ++q)
                v[q] = *(const unsigned short*)&hn8[(size_t)sn[q] * PD + c0];
#pragma unroll
            for (int q = 0; q < 16; ++q) {
                f32x2 f = __builtin_amdgcn_cvt_pk_f32_fp8(v[q], false);
                a0 += f[0];
                a1 += f[1];
            }
        }
        for (; e + 8 <= end; e += 8) {
            int sn[8];
#pragma unroll
            for (int q = 0; q < 8; ++q) sn[q] = srcs[e + q];
            uint32_t v[8];
#pragma unroll
            for (int q = 0; q < 8; ++q)
                v[q] = *(const unsigned short*)&hn8[(size_t)sn[q] * PD + c0];
#pragma unroll
            for (int q = 0; q < 8; ++q) {
                f32x2 f = __builtin_amdgcn_cvt_pk_f32_fp8(v[q], false);
                a0 += f[0];
                a1 += f[1];
            }
        }
        for (; e < end; ++e) {
            int sn = srcs[e];
            uint32_t v = *(const unsigned short*)&hn8[(size_t)sn * PD + c0];
            f32x2 f = __builtin_amdgcn_cvt_pk_f32_fp8(v, false);
            a0 += f[0];
            a1 += f[1];
        }
        uint32_t v = *(const unsigned short*)&hn8[(size_t)node * PD + c0];  // self loop
        f32x2 f = __builtin_amdgcn_cvt_pk_f32_fp8(v, false);
        a0 += f[0];
        a1 += f[1];
        float dd = dis[node];
        a0 = fmaxf(fmaf(a0, dd, bg0), 0.f);
        a1 = fmaxf(fmaf(a1, dd, bg1), 0.f);
        s0 += a0;
        s1 += a1;
    }
    atomicAdd(&sums[(size_t)curb * PD + c0], s0);
    atomicAdd(&sums[(size_t)curb * PD + c0 + 1], s1);
}

// ---------------- dense partial: P[row][kc][c] = A[row][kc*256:(kc+1)*256] @ W[.., c] ----------------
__global__ __launch_bounds__(256) void k_lin_part(const float* __restrict__ A,
                                                  const float* __restrict__ W,
                                                  float* __restrict__ P,
                                                  int K) {
    const int row = blockIdx.x;
    const int kc = blockIdx.y;
    const int c0 = threadIdx.x * 2;
    const float* a = A + (size_t)row * K + kc * 256;
    const float* wp = W + (size_t)kc * 256 * PD + c0;
    float acc0 = 0.f, acc1 = 0.f, acc2 = 0.f, acc3 = 0.f;
    float acc4 = 0.f, acc5 = 0.f, acc6 = 0.f, acc7 = 0.f;
#pragma unroll 4
    for (int k = 0; k < 256; k += 8) {
        float a0 = a[k + 0], a1 = a[k + 1], a2 = a[k + 2], a3 = a[k + 3];
        float a4 = a[k + 4], a5 = a[k + 5], a6 = a[k + 6], a7 = a[k + 7];
        float2 w0 = *(const float2*)&wp[(size_t)(k + 0) * PD];
        float2 w1 = *(const float2*)&wp[(size_t)(k + 1) * PD];
        float2 w2 = *(const float2*)&wp[(size_t)(k + 2) * PD];
        float2 w3 = *(const float2*)&wp[(size_t)(k + 3) * PD];
        float2 w4 = *(const float2*)&wp[(size_t)(k + 4) * PD];
        float2 w5 = *(const float2*)&wp[(size_t)(k + 5) * PD];
        float2 w6 = *(const float2*)&wp[(size_t)(k + 6) * PD];
        float2 w7 = *(const float2*)&wp[(size_t)(k + 7) * PD];
        acc0 = fmaf(a0, w0.x, acc0); acc1 = fmaf(a0, w0.y, acc1);
        acc2 = fmaf(a1, w1.x, acc2); acc3 = fmaf(a1, w1.y, acc3);
        acc4 = fmaf(a2, w2.x, acc4); acc5 = fmaf(a2, w2.y, acc5);
        acc6 = fmaf(a3, w3.x, acc6); acc7 = fmaf(a3, w3.y, acc7);
        acc0 = fmaf(a4, w4.x, acc0); acc1 = fmaf(a4, w4.y, acc1);
        acc2 = fmaf(a5, w5.x, acc2); acc3 = fmaf(a5, w5.y, acc3);
        acc4 = fmaf(a6, w6.x, acc4); acc5 = fmaf(a6, w6.y, acc5);
        acc6 = fmaf(a7, w7.x, acc6); acc7 = fmaf(a7, w7.y, acc7);
    }
    float r0 = (acc0 + acc2) + (acc4 + acc6);
    float r1 = (acc1 + acc3) + (acc5 + acc7);
    P[((size_t)row * 4 + kc) * PD + c0] = r0;
    P[((size_t)row * 4 + kc) * PD + c0 + 1] = r1;
}

// ---------------- reduce partials + (mean-scale) + bias + relu ----------------
__global__ __launch_bounds__(256) void k_lin_red(const float* __restrict__ P,
                                                 const float* __restrict__ bias,
                                                 float* __restrict__ C,
                                                 int nch, int ldc, int relu,
                                                 const int* __restrict__ cnts) {
    const int row = blockIdx.x;
    const int c0 = threadIdx.x * 2;
    const float* p = P + (size_t)row * 4 * PD + c0;
    float r0 = p[0], r1 = p[1];
    if (nch > 1) { r0 += p[PD];     r1 += p[PD + 1]; }
    if (nch > 2) { r0 += p[2 * PD]; r1 += p[2 * PD + 1]; }
    if (nch > 3) { r0 += p[3 * PD]; r1 += p[3 * PD + 1]; }
    float s = 1.f;
    if (cnts) s = 1.f / fmaxf((float)cnts[row], 1.f);
    r0 = fmaf(r0, s, bias[c0]);
    r1 = fmaf(r1, s, bias[c0 + 1]);
    if (relu) { r0 = fmaxf(r0, 0.f); r1 = fmaxf(r1, 0.f); }
    C[(size_t)row * ldc + c0] = r0;
    C[(size_t)row * ldc + c0 + 1] = r1;
}

// ---------------- dot: y[row] = A[row][:K] @ w + b ----------------
__global__ void k_dot(const float* __restrict__ A, const float* __restrict__ w,
                      const float* __restrict__ b, float* __restrict__ y, int K) {
    int row = blockIdx.x;
    int t = threadIdx.x;   // 64
    float s = 0.f;
    for (int k = t; k < K; k += 64) s = fmaf(A[(size_t)row * K + k], w[k], s);
    for (int off = 32; off; off >>= 1) s += __shfl_down(s, off);
    if (t == 0) y[row] = s + b[0];
}

// ---------------- logits + BCE loss ----------------
__global__ void k_final(const float* __restrict__ yi, const float* __restrict__ ys,
                        const float* __restrict__ ans, float* __restrict__ out) {
    __shared__ float red[128];
    int t = threadIdx.x;   // 128
    float l = fmaxf(yi[t], ys[t]);
    out[t] = l;
    float li = fmaxf(l, 0.f) + log1pf(expf(-fabsf(l))) - l * ans[t];
    red[t] = li;
    __syncthreads();
    for (int off = 64; off; off >>= 1) {
        if (t < off) red[t] += red[t + off];
        __syncthreads();
    }
    if (t == 0) out[BATCH] = red[0] / (float)BATCH;
}

extern "C" void kernel_launch(void* const* d_in, const int* in_sizes, int n_in,
                              void* d_out, int out_size, void* d_ws, size_t ws_size,
                              hipStream_t stream) {
    const float* image_features = (const float*)d_in[0];
    const float* text_features  = (const float*)d_in[1];
    const float* answer         = (const float*)d_in[2];
    const float* x_nodes        = (const float*)d_in[3];
    const int*   edge_index     = (const int*)d_in[4];
    const int*   batch_vec      = (const int*)d_in[5];
    const float* W_img = (const float*)d_in[6];
    const float* b_img = (const float*)d_in[7];
    const float* W_txt = (const float*)d_in[8];
    const float* b_txt = (const float*)d_in[9];
    const float* W1  = (const float*)d_in[10];
    const float* b1  = (const float*)d_in[11];
    const float* W2  = (const float*)d_in[12];
    const float* b2  = (const float*)d_in[13];
    const float* Wg  = (const float*)d_in[14];
    const float* bg  = (const float*)d_in[15];
    const float* Ws1 = (const float*)d_in[16];
    const float* bs1 = (const float*)d_in[17];
    const float* Ws2 = (const float*)d_in[18];
    const float* bs2 = (const float*)d_in[19];
    float* out = (float*)d_out;

    char* base = (char*)d_ws;
    size_t cur = 0;
    auto alloc = [&](size_t bytes) -> void* {
        void* r = base + cur;
        cur = (cur + bytes + 255) & ~(size_t)255;
        return r;
    };
    unsigned short* WgT = (unsigned short*)alloc((size_t)PD * PD * 2);
    uint8_t* hn8   = (uint8_t*)alloc((size_t)N_NODES * PD);
    int*   deg     = (int*)alloc((size_t)N_NODES * 4);
    float* dis     = (float*)alloc((size_t)N_NODES * 4);
    int*   row_ptr = (int*)alloc((size_t)(N_NODES + 1) * 4);
    int*   fill    = (int*)alloc((size_t)N_NODES * 4);
    int*   srcs    = (int*)alloc((size_t)N_EDGES * 4);
    float* sums    = (float*)alloc((size_t)BATCH * PD * 4);
    int*   cnts    = (int*)alloc((size_t)BATCH * 4);
    float* Ppart   = (float*)alloc((size_t)BATCH * 4 * PD * 4);
    float* combined = (float*)alloc((size_t)BATCH * 1024 * 4);
    float* h1      = (float*)alloc((size_t)BATCH * PD * 4);
    float* hs      = (float*)alloc((size_t)BATCH * PD * 4);
    float* yi      = (float*)alloc((size_t)BATCH * 4);
    float* ys      = (float*)alloc((size_t)BATCH * 4);

    // symbolic-branch preprocessing
    hipLaunchKernelGGL(k_wgt, dim3(16, 16), dim3(32, 32), 0, stream, Wg, WgT, batch_vec, cnts);
    hipLaunchKernelGGL(k_init, dim3(256), dim3(256), 0, stream, deg, fill, sums);
    hipLaunchKernelGGL(k_deg, dim3(4096), dim3(256), 0, stream, edge_index, deg);
    hipLaunchKernelGGL(k_scan, dim3(1), dim3(1024), 0, stream, deg, row_ptr, dis);
    hipLaunchKernelGGL(k_scatter, dim3(4096), dim3(256), 0, stream, edge_index, row_ptr, fill, srcs);
    hipLaunchKernelGGL(k_gemm, dim3(N_NODES / 128, PD / 256), dim3(256), 0, stream,
                       x_nodes, WgT, dis, hn8);
    hipLaunchKernelGGL(k_agg, dim3(N_NODES / NPB), dim3(256), 0, stream,
                       hn8, dis, bg, row_ptr, srcs, batch_vec, sums);

    // implicit branch: img proj -> combined[:,0:512]
    hipLaunchKernelGGL(k_lin_part, dim3(BATCH, 3), dim3(256), 0, stream,
                       image_features, W_img, Ppart, CLIPD);
    hipLaunchKernelGGL(k_lin_red, dim3(BATCH), dim3(256), 0, stream,
                       Ppart, b_img, combined, 3, 1024, 0, (const int*)nullptr);
    // txt proj -> combined[:,512:1024]
    hipLaunchKernelGGL(k_lin_part, dim3(BATCH, 3), dim3(256), 0, stream,
                       text_features, W_txt, Ppart, CLIPD);
    hipLaunchKernelGGL(k_lin_red, dim3(BATCH), dim3(256), 0, stream,
                       Ppart, b_txt, combined + PD, 3, 1024, 0, (const int*)nullptr);
    // classifier layer 1 (K=1024)
    hipLaunchKernelGGL(k_lin_part, dim3(BATCH, 4), dim3(256), 0, stream,
                       combined, W1, Ppart, 1024);
    hipLaunchKernelGGL(k_lin_red, dim3(BATCH), dim3(256), 0, stream,
                       Ppart, b1, h1, 4, PD, 1, (const int*)nullptr);
    hipLaunchKernelGGL(k_dot, dim3(BATCH), dim3(64), 0, stream, h1, W2, b2, yi, PD);

    // symbolic classifier (mean-pool folded via cnts), K=512
    hipLaunchKernelGGL(k_lin_part, dim3(BATCH, 2), dim3(256), 0, stream,
                       sums, Ws1, Ppart, PD);
    hipLaunchKernelGGL(k_lin_red, dim3(BATCH), dim3(256), 0, stream,
                       Ppart, bs1, hs, 2, PD, 1, cnts);
    hipLaunchKernelGGL(k_dot, dim3(BATCH), dim3(64), 0, stream, hs, Ws2, bs2, ys, PD);

    // fuse
    hipLaunchKernelGGL(k_final, dim3(1), dim3(128), 0, stream, yi, ys, answer, out);
}